// Round 7
// baseline (347.160 us; speedup 1.0000x reference)
//
#include <hip/hip_runtime.h>
#include <hip/hip_bf16.h>
#include <stdint.h>
#include <stddef.h>

typedef __bf16 bf16x8 __attribute__((ext_vector_type(8)));
typedef float f32x4 __attribute__((ext_vector_type(4)));
typedef int i32x4 __attribute__((ext_vector_type(4)));
typedef __hip_bfloat16 bf16_t;

#define BM 128
#define BN 128
#define BK 64      // bf16 elements per K-tile (128 B rows)
#define BKQ 128    // i8 elements per K-tile (128 B rows -- same geometry)
#define THREADS 256

// async global->LDS, 16B per lane. LDS dest must be wave-uniform-base + lane*16.
__device__ __forceinline__ void stage16(const void* g, void* l) {
  __builtin_amdgcn_global_load_lds(
      (const __attribute__((address_space(1))) uint32_t*)g,
      (__attribute__((address_space(3))) uint32_t*)l, 16, 0, 0);
}

__device__ __forceinline__ unsigned pk2(float x, float y) {
  bf16_t a = __float2bfloat16(x);
  bf16_t b = __float2bfloat16(y);
  unsigned short ua = *(unsigned short*)&a;
  unsigned short ub = *(unsigned short*)&b;
  return (unsigned)ua | ((unsigned)ub << 16);
}

// XCD chunk swizzle (R5): HW round-robins linear wgid across 8 XCDs; remap so
// each XCD owns a CONTIGUOUS chunk of work-ids. With x (m-tile) fastest in the
// work linearization, consecutive work-ids share the same B-panel -> each
// B-panel gets a single-XCD L2 home instead of being pulled into all 8.
// CONTRACT: total grid size % 8 == 0 (all call sites are 512 or 1024).
__device__ __forceinline__ void xcd_swz(unsigned& bx, unsigned& by, unsigned& bz) {
  const unsigned nx = gridDim.x, ny = gridDim.y;
  unsigned wg = blockIdx.x + nx * (blockIdx.y + ny * blockIdx.z);
  unsigned cpx = (nx * ny * gridDim.z) >> 3;
  unsigned work = (wg & 7) * cpx + (wg >> 3);
  bx = work % nx;
  unsigned rem = work / nx;
  by = rem % ny;
  bz = rem / ny;
}

// ---------------- hierarchical absmax commit (1 atomic per BLOCK) ----------
// R7 lesson: WAVE-level atomics to one address serialize (~12ns each across
// XCDs); 8192 of them = 97us. Block-level (512-1024 staggered) is ~free.
__device__ __forceinline__ void block_max_commit(float m, unsigned* slot) {
  __shared__ float red[4];
#pragma unroll
  for (int off = 32; off > 0; off >>= 1)
    m = fmaxf(m, __shfl_xor(m, off, 64));
  if ((threadIdx.x & 63) == 0) red[threadIdx.x >> 6] = m;
  __syncthreads();
  if (threadIdx.x == 0) {
    float mm = fmaxf(fmaxf(red[0], red[1]), fmaxf(red[2], red[3]));
    atomicMax(slot, __float_as_uint(mm));
  }
}

// ---------------- bf16 GEMM (R3/R6-verified core; support GEMMs) -------------
// C = A @ Bt^T. A:[M,K] row-major bf16 (row stride K, extent Kc). Bt:[N,K].
// OUT_MODE 0: bf16 row-major [M,N]; 1: bf16 transposed [N,M]; 2: f32 row-major.
// blockIdx.z = kz*4 + b (B=4). Output chunk at z*sC.
// AMAX: fuse per-tensor absmax of outputs (block max -> 1 atomic); requires
// full-K single pass (no split-K) at the call site. Max is over pre-bf16-round
// f32 values; quant8 clamps to +-127 pre-rint so the <=0.4% ULP gap is benign.
// DO NOT MODIFY staging/LDS scheme (R4: 32-row fragments -> 1.7e7 conflicts).
template <int OUT_MODE, bool RELU, bool AMAX>
__global__ void gemm_bt(const bf16_t* __restrict__ A, const bf16_t* __restrict__ Bt,
                        void* __restrict__ Cv, int M, int N, int K, int Kc,
                        long sA, long sB, long sC, unsigned* __restrict__ amax) {
  __shared__ __align__(16) char lds[(BM + BN) * BK * 2];  // 32 KB
  char* ldsA = lds;
  char* ldsB = lds + BM * BK * 2;

  unsigned bx, by, bz;
  xcd_swz(bx, by, bz);

  const int t = threadIdx.x;
  const int lane = t & 63;
  const int w = t >> 6;
  const int wm = w >> 1, wn = w & 1;
  const int quad = lane >> 4, l15 = lane & 15;
  const int m0 = bx * BM;
  const int n0 = by * BN;
  const int z = bz;
  const int b = z & 3;
  const int kz = z >> 2;

  const bf16_t* Ab = A + (size_t)b * sA + (size_t)kz * Kc;
  const bf16_t* Bb = Bt + (size_t)b * sB + (size_t)kz * Kc;

  size_t aSrc[4], bSrc[4];
#pragma unroll
  for (int i = 0; i < 4; ++i) {
    int c = i * 256 + t;
    int r = c >> 3;
    int kcs = (c & 7) ^ (r & 7);
    aSrc[i] = (size_t)(m0 + r) * K + (size_t)kcs * 8;
    bSrc[i] = (size_t)(n0 + r) * K + (size_t)kcs * 8;
  }

  f32x4 acc[4][4];
#pragma unroll
  for (int mi = 0; mi < 4; ++mi)
#pragma unroll
    for (int ni = 0; ni < 4; ++ni)
      acc[mi][ni] = f32x4{0.f, 0.f, 0.f, 0.f};

  const int aRowB = (wm * 64 + l15) * (BK * 2);
  const int bRowB = (wn * 64 + l15) * (BK * 2);
  const int xc0 = (quad ^ (lane & 7)) * 16;

  for (int k0 = 0; k0 < Kc; k0 += BK) {
#pragma unroll
    for (int i = 0; i < 4; ++i) {
      stage16(Ab + aSrc[i] + k0, ldsA + (i * 256 + t) * 16);
      stage16(Bb + bSrc[i] + k0, ldsB + (i * 256 + t) * 16);
    }
    __syncthreads();

#pragma unroll
    for (int ks = 0; ks < 2; ++ks) {
      const int xo = xc0 ^ (ks * 64);
      bf16x8 af[4], bfr[4];
#pragma unroll
      for (int mi = 0; mi < 4; ++mi)
        af[mi] = *(const bf16x8*)(ldsA + aRowB + mi * 2048 + xo);
#pragma unroll
      for (int ni = 0; ni < 4; ++ni)
        bfr[ni] = *(const bf16x8*)(ldsB + bRowB + ni * 2048 + xo);
#pragma unroll
      for (int mi = 0; mi < 4; ++mi)
#pragma unroll
        for (int ni = 0; ni < 4; ++ni)
          acc[mi][ni] = __builtin_amdgcn_mfma_f32_16x16x32_bf16(
              af[mi], bfr[ni], acc[mi][ni], 0, 0, 0);
    }
    __syncthreads();
  }

  const int mBase = m0 + wm * 64 + quad * 4;
  const int nBase = n0 + wn * 64 + l15;
  float mval = 0.f;

  if (OUT_MODE == 1) {
    bf16_t* Ct = (bf16_t*)Cv + (size_t)z * sC;
#pragma unroll
    for (int ni = 0; ni < 4; ++ni) {
      size_t colOff = (size_t)(nBase + ni * 16) * (size_t)M;
#pragma unroll
      for (int mi = 0; mi < 4; ++mi) {
        int rr = mBase + mi * 16;
        float v0 = acc[mi][ni][0], v1 = acc[mi][ni][1];
        float v2 = acc[mi][ni][2], v3 = acc[mi][ni][3];
        if (RELU) {
          v0 = fmaxf(v0, 0.f); v1 = fmaxf(v1, 0.f);
          v2 = fmaxf(v2, 0.f); v3 = fmaxf(v3, 0.f);
        }
        if (AMAX) {
          mval = fmaxf(mval, fmaxf(fmaxf(fabsf(v0), fabsf(v1)),
                                   fmaxf(fabsf(v2), fabsf(v3))));
        }
        uint2 pkv;
        pkv.x = pk2(v0, v1);
        pkv.y = pk2(v2, v3);
        *(uint2*)(Ct + colOff + rr) = pkv;
      }
    }
  } else if (OUT_MODE == 0) {
    bf16_t* C = (bf16_t*)Cv + (size_t)z * sC;
#pragma unroll
    for (int mi = 0; mi < 4; ++mi) {
#pragma unroll
      for (int j = 0; j < 4; ++j) {
        size_t rowOff = (size_t)(mBase + mi * 16 + j) * (size_t)N;
#pragma unroll
        for (int ni = 0; ni < 4; ++ni) {
          float v = acc[mi][ni][j];
          if (RELU) v = fmaxf(v, 0.f);
          if (AMAX) mval = fmaxf(mval, fabsf(v));
          C[rowOff + nBase + ni * 16] = __float2bfloat16(v);
        }
      }
    }
  } else {
    float* C = (float*)Cv + (size_t)z * sC;
#pragma unroll
    for (int mi = 0; mi < 4; ++mi) {
#pragma unroll
      for (int j = 0; j < 4; ++j) {
        size_t rowOff = (size_t)(mBase + mi * 16 + j) * (size_t)N;
#pragma unroll
        for (int ni = 0; ni < 4; ++ni) {
          float v = acc[mi][ni][j];
          if (RELU) v = fmaxf(v, 0.f);
          C[rowOff + nBase + ni * 16] = v;
        }
      }
    }
  }

  if (AMAX) block_max_commit(mval, amax);
}

// ---------------- int8 GEMM (adjacency GEMMs; R7-validated) ----------------
// BKQ=128 i8 = 128 B rows = same staging geometry as bf16 core. K-step = 64 i8
// = 4 chunks. A: AW_q (static scale 127). B: per-tensor scale mx in *slot.
// Epilogue: v = acc * mx / 127^2. Output bf16 row-major partial at z*sC.
// R4 split-K policy: minimize partial-C traffic. SK=1 (direct write) when the
// no-split grid still gives >=2 blocks/CU; else SK=2.
__global__ void gemm_i8(const int8_t* __restrict__ A, const int8_t* __restrict__ Bt,
                        bf16_t* __restrict__ C, int M, int N, int K, int Kc,
                        long sA, long sB, long sC,
                        const unsigned* __restrict__ slot) {
  __shared__ __align__(16) char lds[(BM + BN) * BKQ];  // 32 KB
  char* ldsA = lds;
  char* ldsB = lds + BM * BKQ;

  unsigned bx, by, bz;
  xcd_swz(bx, by, bz);

  const int t = threadIdx.x;
  const int lane = t & 63;
  const int w = t >> 6;
  const int wm = w >> 1, wn = w & 1;
  const int quad = lane >> 4, l15 = lane & 15;
  const int m0 = bx * BM;
  const int n0 = by * BN;
  const int z = bz;
  const int b = z & 3;
  const int kz = z >> 2;

  const int8_t* Ab = A + (size_t)b * sA + (size_t)kz * Kc;
  const int8_t* Bb = Bt + (size_t)b * sB + (size_t)kz * Kc;

  size_t aSrc[4], bSrc[4];
#pragma unroll
  for (int i = 0; i < 4; ++i) {
    int c = i * 256 + t;
    int r = c >> 3;
    int kcs = (c & 7) ^ (r & 7);
    aSrc[i] = (size_t)(m0 + r) * K + (size_t)kcs * 16;  // 16 i8 per chunk
    bSrc[i] = (size_t)(n0 + r) * K + (size_t)kcs * 16;
  }

  i32x4 acc[4][4];
#pragma unroll
  for (int mi = 0; mi < 4; ++mi)
#pragma unroll
    for (int ni = 0; ni < 4; ++ni)
      acc[mi][ni] = i32x4{0, 0, 0, 0};

  const int aRowB = (wm * 64 + l15) * BKQ;
  const int bRowB = (wn * 64 + l15) * BKQ;
  const int xc0 = (quad ^ (lane & 7)) * 16;

  for (int k0 = 0; k0 < Kc; k0 += BKQ) {
#pragma unroll
    for (int i = 0; i < 4; ++i) {
      stage16(Ab + aSrc[i] + k0, ldsA + (i * 256 + t) * 16);
      stage16(Bb + bSrc[i] + k0, ldsB + (i * 256 + t) * 16);
    }
    __syncthreads();

#pragma unroll
    for (int ks = 0; ks < 2; ++ks) {        // two K=64 MFMA steps per BKQ=128
      const int xo = xc0 ^ (ks * 64);
      i32x4 af[4], bfr[4];
#pragma unroll
      for (int mi = 0; mi < 4; ++mi)
        af[mi] = *(const i32x4*)(ldsA + aRowB + mi * 2048 + xo);
#pragma unroll
      for (int ni = 0; ni < 4; ++ni)
        bfr[ni] = *(const i32x4*)(ldsB + bRowB + ni * 2048 + xo);
#pragma unroll
      for (int mi = 0; mi < 4; ++mi)
#pragma unroll
        for (int ni = 0; ni < 4; ++ni)
          acc[mi][ni] = __builtin_amdgcn_mfma_i32_16x16x64_i8(
              af[mi], bfr[ni], acc[mi][ni], 0, 0, 0);
    }
    __syncthreads();
  }

  const float mx = fmaxf(__uint_as_float(*slot), 1e-20f);
  const float sc = mx * (1.0f / 16129.0f);  // / (127*127)

  const int mBase = m0 + wm * 64 + quad * 4;
  const int nBase = n0 + wn * 64 + l15;
  bf16_t* Cb = C + (size_t)z * sC;
#pragma unroll
  for (int mi = 0; mi < 4; ++mi) {
#pragma unroll
    for (int j = 0; j < 4; ++j) {
      size_t rowOff = (size_t)(mBase + mi * 16 + j) * (size_t)N;
#pragma unroll
      for (int ni = 0; ni < 4; ++ni)
        Cb[rowOff + nBase + ni * 16] = __float2bfloat16((float)acc[mi][ni][j] * sc);
    }
  }
}

// Sum SK bf16 partial chunks (stride tot) in fp32; write bf16 or f32.
// AMAX: fuse per-tensor absmax of the summed outputs (block max -> 1 atomic).
// CONTRACT: (tot/8) % (gridDim.x * blockDim.x * 2) == 0 at every call site.
template <int SK, bool F32OUT, bool AMAX>
__global__ void reduce_k(const bf16_t* __restrict__ pp, void* __restrict__ out,
                         size_t tot, unsigned* __restrict__ amax) {
  const int bs = blockDim.x;
  size_t base = (size_t)blockIdx.x * bs * 2 + threadIdx.x;  // 8-elem group idx
  bf16x8 v[2][SK];
#pragma unroll
  for (int u = 0; u < 2; ++u) {
    size_t g = base + (size_t)u * bs;
#pragma unroll
    for (int kz = 0; kz < SK; ++kz)
      v[u][kz] = *(const bf16x8*)(pp + (size_t)kz * tot + g * 8);
  }
  float mval = 0.f;
#pragma unroll
  for (int u = 0; u < 2; ++u) {
    size_t g = base + (size_t)u * bs;
    float s[8];
#pragma unroll
    for (int j = 0; j < 8; ++j) s[j] = 0.f;
#pragma unroll
    for (int kz = 0; kz < SK; ++kz)
#pragma unroll
      for (int j = 0; j < 8; ++j) s[j] += (float)v[u][kz][j];
    if (AMAX) {
#pragma unroll
      for (int j = 0; j < 8; ++j) mval = fmaxf(mval, fabsf(s[j]));
    }
    if (F32OUT) {
      float* o = (float*)out + g * 8;
      float4 r0{s[0], s[1], s[2], s[3]};
      float4 r1{s[4], s[5], s[6], s[7]};
      ((float4*)o)[0] = r0;
      ((float4*)o)[1] = r1;
    } else {
      uint4 r;
      r.x = pk2(s[0], s[1]);
      r.y = pk2(s[2], s[3]);
      r.z = pk2(s[4], s[5]);
      r.w = pk2(s[6], s[7]);
      *(uint4*)((bf16_t*)out + g * 8) = r;
    }
  }
  if (AMAX) block_max_commit(mval, amax);
}

// ---------------- fused prep kernel (one launch, partitioned grid) ----------
// Segment A (blocks [0,512)):          absmax(x) -> SX  (grid-stride, 2 iters)
// Segment B (blocks [512,512+3584)):   W1/W2/W3 transpose+cast. 3584*256 =
//                                      917504 = n1+n2+n3 EXACTLY (R2 bug: 5120
//                                      here overran W3T by ~1MB, clobbering SC).
// Segment C (blocks [4096,4096+16384)): AW_q = round(adj*S*127), 1 float4/thr.
//   R5/R6: NONTEMPORAL loads on adj/S (134MB read-once-per-replay stream;
//   testing cache-allocation-pollution theory for the ~2.9 TB/s cap seen in
//   R0/R1/R3). nt builtin needs ext_vector ptr, not HIP_vector_type (R5 fail).
//   AWQ store stays cached (re-read 3x by gemms).
// SX/SH1/SST3 slots are zeroed by a hipMemsetAsync node BEFORE this kernel.
#define PREP_AMX 512
#define PREP_C3  3584   // (256*512 + 512*1024 + 1024*256) / 256  == 3584
#define PREP_MC  16384  // (4096*4096/4) / 256

__global__ void prep_kernel(const float* __restrict__ adj, const float* __restrict__ S,
                            int8_t* __restrict__ o,
                            const float* __restrict__ x, size_t n4x,
                            unsigned* __restrict__ SX,
                            const float* __restrict__ W1, const float* __restrict__ W2,
                            const float* __restrict__ W3, bf16_t* __restrict__ W1T,
                            bf16_t* __restrict__ W2T, bf16_t* __restrict__ W3T) {
  const int bid = blockIdx.x;
  const int tid = threadIdx.x;

  if (bid < PREP_AMX) {
    // absmax over x (f32), 4 float4 loads in flight per iter
    size_t base = (size_t)bid * (256 * 4) + tid;
    const size_t stride = (size_t)PREP_AMX * 256 * 4;
    float m = 0.f;
    for (; base + 3 * 256 < n4x; base += stride) {
      float4 v[4];
#pragma unroll
      for (int j = 0; j < 4; ++j) v[j] = ((const float4*)x)[base + (size_t)j * 256];
#pragma unroll
      for (int j = 0; j < 4; ++j)
        m = fmaxf(m, fmaxf(fmaxf(fabsf(v[j].x), fabsf(v[j].y)),
                           fmaxf(fabsf(v[j].z), fabsf(v[j].w))));
    }
    block_max_commit(m, SX);
  } else if (bid < PREP_AMX + PREP_C3) {
    const int n1 = 256 * 512;
    const int n2 = 512 * 1024;
    const int n3 = 1024 * 256;
    int idx = (bid - PREP_AMX) * 256 + tid;
    if (idx < n1) {
      int K = 256, H = 512;
      int h = idx / K, k = idx - h * K;
      W1T[idx] = __float2bfloat16(W1[(size_t)k * H + h]);
    } else if (idx < n1 + n2) {
      int i = idx - n1;
      int K = 512, H = 1024;
      int h = i / K, k = i - h * K;
      W2T[i] = __float2bfloat16(W2[(size_t)k * H + h]);
    } else if (idx < n1 + n2 + n3) {
      int i = idx - n1 - n2;
      int K = 1024, H = 256;
      int h = i / K, k = i - h * K;
      W3T[i] = __float2bfloat16(W3[(size_t)k * H + h]);
    }
  } else {
    int i = (bid - PREP_AMX - PREP_C3) * 256 + tid;
    f32x4 av = __builtin_nontemporal_load((const f32x4*)adj + i);
    f32x4 sv = __builtin_nontemporal_load((const f32x4*)S + i);
    float v0 = av[0] * sv[0] * 127.f, v1 = av[1] * sv[1] * 127.f;
    float v2 = av[2] * sv[2] * 127.f, v3 = av[3] * sv[3] * 127.f;
    int q0 = (int)rintf(fminf(fmaxf(v0, -127.f), 127.f));
    int q1 = (int)rintf(fminf(fmaxf(v1, -127.f), 127.f));
    int q2 = (int)rintf(fminf(fmaxf(v2, -127.f), 127.f));
    int q3 = (int)rintf(fminf(fmaxf(v3, -127.f), 127.f));
    unsigned p = (unsigned)(q0 & 255) | ((unsigned)(q1 & 255) << 8) |
                 ((unsigned)(q2 & 255) << 16) | ((unsigned)(q3 & 255) << 24);
    ((unsigned*)o)[i] = p;
  }
}

// x [B][4096][256] f32 -> xt [B][256][4096] i8 (scale 127/mx from slot)
__global__ void transpose_quant_x(const float* __restrict__ x, int8_t* __restrict__ xt,
                                  const unsigned* __restrict__ slot) {
  __shared__ float tile[32][33];
  const int N = 4096, F = 256;
  float qs = 127.0f / fmaxf(__uint_as_float(*slot), 1e-20f);
  int n0 = blockIdx.x * 32, f0 = blockIdx.y * 32, b = blockIdx.z;
  const float* xb = x + (size_t)b * N * F;
  int8_t* xtb = xt + (size_t)b * N * F;
  int tx = threadIdx.x & 31, ty = threadIdx.x >> 5;  // 32 x 8
#pragma unroll
  for (int i = 0; i < 32; i += 8)
    tile[ty + i][tx] = xb[(size_t)(n0 + ty + i) * F + f0 + tx];
  __syncthreads();
#pragma unroll
  for (int i = 0; i < 32; i += 8) {
    float v = tile[tx][ty + i] * qs;
    xtb[(size_t)(f0 + ty + i) * N + n0 + tx] =
        (int8_t)(int)rintf(fminf(fmaxf(v, -127.f), 127.f));
  }
}

// bf16 -> i8 with scale 127/mx from slot; 4 groups of 8 elems per thread.
// CONTRACT: n8 % (gridDim.x * blockDim.x * 4) == 0 at every call site.
__global__ void quant8(const bf16_t* __restrict__ in, int8_t* __restrict__ out,
                       const unsigned* __restrict__ slot, size_t n8) {
  const int bs = blockDim.x;
  size_t base = (size_t)blockIdx.x * bs * 4 + threadIdx.x;
  float qs = 127.0f / fmaxf(__uint_as_float(*slot), 1e-20f);
  bf16x8 v[4];
#pragma unroll
  for (int j = 0; j < 4; ++j)
    v[j] = *(const bf16x8*)(in + (base + (size_t)j * bs) * 8);
#pragma unroll
  for (int j = 0; j < 4; ++j) {
    unsigned lo = 0, hi = 0;
#pragma unroll
    for (int e = 0; e < 4; ++e) {
      int q = (int)rintf(fminf(fmaxf((float)v[j][e] * qs, -127.f), 127.f));
      lo |= (unsigned)(q & 255) << (8 * e);
    }
#pragma unroll
    for (int e = 0; e < 4; ++e) {
      int q = (int)rintf(fminf(fmaxf((float)v[j][4 + e] * qs, -127.f), 127.f));
      hi |= (unsigned)(q & 255) << (8 * e);
    }
    uint2 r{lo, hi};
    ((uint2*)out)[base + (size_t)j * bs] = r;
  }
}

extern "C" void kernel_launch(void* const* d_in, const int* in_sizes, int n_in,
                              void* d_out, int out_size, void* d_ws, size_t ws_size,
                              hipStream_t stream) {
  const float* x   = (const float*)d_in[0];  // [4, 4096, 256]
  const float* adj = (const float*)d_in[1];  // [4096, 4096]
  const float* S   = (const float*)d_in[2];  // [4096, 4096]
  const float* W1  = (const float*)d_in[3];  // [256, 512]
  const float* W2  = (const float*)d_in[4];  // [512, 1024]
  const float* W3  = (const float*)d_in[5];  // [1024, 256]

  const int N = 4096, F = 256, H1 = 512, H2 = 1024, NC = 256, B = 4;

  // Chain (adjacency GEMMs i8, support GEMMs bf16), R7 workspace (~98.5 MiB):
  char* ws = (char*)d_ws;
  int8_t* AWQ  = (int8_t*)ws; ws += (size_t)N * N;           // 16.8 MB
  bf16_t* SCR  = (bf16_t*)ws; ws += (size_t)B * N * H2 * 2;  // 33.5 MB partials/H2B
  int8_t* XQT  = (int8_t*)ws; ws += (size_t)B * F * N;       //  4.2 MB
  bf16_t* BufY = (bf16_t*)ws; ws += (size_t)B * N * H1 * 2;  // 16.8 MB G1/G2/ST3T
  bf16_t* BufZ = (bf16_t*)ws; ws += (size_t)B * N * H1 * 2;  // 16.8 MB H1T/st3 partials
  int8_t* QS   = (int8_t*)ws; ws += (size_t)B * H1 * N;      //  8.4 MB H1Q/ST3Q
  bf16_t* W1T  = (bf16_t*)ws; ws += (size_t)F * H1 * 2;
  bf16_t* W2T  = (bf16_t*)ws; ws += (size_t)H1 * H2 * 2;
  bf16_t* W3T  = (bf16_t*)ws; ws += (size_t)H2 * NC * 2;
  unsigned* SC = (unsigned*)ws;                              // 3 scale slots
  unsigned* SX = SC, *SH1 = SC + 1, *SST3 = SC + 2;

  bf16_t* G1 = BufY, *G2 = BufY, *ST3T = BufY;
  bf16_t* H1T = BufZ;
  bf16_t* H2B = SCR;
  int8_t* H1Q = QS, *ST3Q = QS;

  dim3 blk(THREADS);

  // prep: zero the 3 scale slots (graph-legal memset node), then one fused
  // kernel: absmax(x) | weight cast3 | AW_q quantize (nt loads).
  (void)hipMemsetAsync(SC, 0, 3 * sizeof(unsigned), stream);
  prep_kernel<<<PREP_AMX + PREP_C3 + PREP_MC, 256, 0, stream>>>(
      adj, S, AWQ, x, (size_t)B * N * F / 4, SX, W1, W2, W3, W1T, W2T, W3T);
  transpose_quant_x<<<dim3(N / 32, F / 32, B), 256, 0, stream>>>(x, XQT, SX);

  // L1: g1 = AWq @ xq, SK=2 -> SCR, reduce -> G1.  Grid (32,2,8) = 512 blocks.
  gemm_i8<<<dim3(N / BM, F / BN, B * 2), blk, 0, stream>>>(
      AWQ, XQT, SCR, N, F, N, N / 2, 0, (long)F * N, (long)N * F, SX);
  // groups = B*N*F/8 = 524,288 ; 1024*256*2 = 524,288 -> exact.
  reduce_k<2, false, false><<<1024, 256, 0, stream>>>(SCR, G1, (size_t)B * N * F, nullptr);
  //     h1^T = relu(g1 @ W1)^T -> H1T, absmax fused into epilogue -> SH1
  gemm_bt<1, true, true><<<dim3(N / BM, H1 / BN, B), blk, 0, stream>>>(
      G1, W1T, H1T, N, H1, F, F, (long)N * F, 0, (long)H1 * N, SH1);
  // n8 = 1,048,576 ; 1024*256*4 = 1,048,576 -> exact single shot.
  quant8<<<1024, 256, 0, stream>>>(H1T, H1Q, SH1, (size_t)B * H1 * N / 8);

  // L2: g2 = AWq @ h1q, NO split-K (direct write -> G2). Grid (32,4,4) = 512.
  gemm_i8<<<dim3(N / BM, H1 / BN, B), blk, 0, stream>>>(
      AWQ, H1Q, G2, N, H1, N, N, 0, (long)H1 * N, (long)N * H1, SH1);
  //     h2 = relu(g2 @ W2) -> H2B (SCR).  Grid (32,8,4) = 1024.
  gemm_bt<0, true, false><<<dim3(N / BM, H2 / BN, B), blk, 0, stream>>>(
      G2, W2T, H2B, N, H2, H1, H1, (long)N * H1, 0, (long)N * H2, nullptr);

  // L3: st3^T = (h2 @ W3)^T, SK=2 -> partials BufZ, reduce+absmax -> ST3T/SST3
  gemm_bt<1, false, false><<<dim3(N / BM, NC / BN, B * 2), blk, 0, stream>>>(
      H2B, W3T, BufZ, N, NC, H2, H2 / 2, (long)N * H2, 0, (long)NC * N, nullptr);
  // groups = 524,288 -> 1024 blocks exact.
  reduce_k<2, false, true><<<1024, 256, 0, stream>>>(BufZ, ST3T, (size_t)B * NC * N, SST3);
  // n8 = 524,288 ; 512*256*4 = 524,288 -> exact single shot.
  quant8<<<512, 256, 0, stream>>>(ST3T, ST3Q, SST3, (size_t)B * NC * N / 8);
  //     out = AWq @ st3q, SK=2 -> partials SCR, reduce f32 -> d_out
  gemm_i8<<<dim3(N / BM, NC / BN, B * 2), blk, 0, stream>>>(
      AWQ, ST3Q, SCR, N, NC, N, N / 2, 0, (long)NC * N, (long)N * NC, SST3);
  // groups = 524,288 -> 1024 blocks exact.
  reduce_k<2, true, false><<<1024, 256, 0, stream>>>(SCR, d_out, (size_t)B * N * NC, nullptr);
}

// Round 8
// 340.073 us; speedup vs baseline: 1.0208x; 1.0208x over previous
//
#include <hip/hip_runtime.h>
#include <hip/hip_bf16.h>
#include <stdint.h>
#include <stddef.h>

typedef __bf16 bf16x8 __attribute__((ext_vector_type(8)));
typedef float f32x4 __attribute__((ext_vector_type(4)));
typedef int i32x4 __attribute__((ext_vector_type(4)));
typedef __hip_bfloat16 bf16_t;

#define BM 128
#define BN 128
#define BK 64      // bf16 elements per K-tile (128 B rows)
#define BKQ 128    // i8 elements per K-tile (128 B rows -- same geometry)
#define THREADS 256

// async global->LDS, 16B per lane. LDS dest must be wave-uniform-base + lane*16.
__device__ __forceinline__ void stage16(const void* g, void* l) {
  __builtin_amdgcn_global_load_lds(
      (const __attribute__((address_space(1))) uint32_t*)g,
      (__attribute__((address_space(3))) uint32_t*)l, 16, 0, 0);
}

__device__ __forceinline__ unsigned pk2(float x, float y) {
  bf16_t a = __float2bfloat16(x);
  bf16_t b = __float2bfloat16(y);
  unsigned short ua = *(unsigned short*)&a;
  unsigned short ub = *(unsigned short*)&b;
  return (unsigned)ua | ((unsigned)ub << 16);
}

// R8 NOTE: XCD chunk swizzle REMOVED. R7 A/B showed applying it to all six
// GEMMs cost ~17us aggregate (gemm_i8 41.8us, MfmaUtil 30%, occ 17.8%) --
// chunked (by,b)-slabs force each XCD to stream the full 16.8MB AWQ through
// its 4MB L2; default round-robin interleave keeps a narrower per-XCD A set.
// Do not re-add without per-gemm counter evidence.

// ---------------- hierarchical absmax commit (1 atomic per BLOCK) ----------
// R7 lesson: WAVE-level atomics to one address serialize (~12ns each across
// XCDs); 8192 of them = 97us. Block-level (512-1024 staggered) is ~free.
__device__ __forceinline__ void block_max_commit(float m, unsigned* slot) {
  __shared__ float red[4];
#pragma unroll
  for (int off = 32; off > 0; off >>= 1)
    m = fmaxf(m, __shfl_xor(m, off, 64));
  if ((threadIdx.x & 63) == 0) red[threadIdx.x >> 6] = m;
  __syncthreads();
  if (threadIdx.x == 0) {
    float mm = fmaxf(fmaxf(red[0], red[1]), fmaxf(red[2], red[3]));
    atomicMax(slot, __float_as_uint(mm));
  }
}

// ---------------- bf16 GEMM (R3/R6-verified core; support GEMMs) -------------
// C = A @ Bt^T. A:[M,K] row-major bf16 (row stride K, extent Kc). Bt:[N,K].
// OUT_MODE 0: bf16 row-major [M,N]; 1: bf16 transposed [N,M]; 2: f32 row-major.
// blockIdx.z = kz*4 + b (B=4). Output chunk at z*sC.
// AMAX: fuse per-tensor absmax of outputs (block max -> 1 atomic); requires
// full-K single pass (no split-K) at the call site. Max is over pre-bf16-round
// f32 values; quant8 clamps to +-127 pre-rint so the <=0.4% ULP gap is benign.
// DO NOT MODIFY staging/LDS scheme (R4: 32-row fragments -> 1.7e7 conflicts).
template <int OUT_MODE, bool RELU, bool AMAX>
__global__ void gemm_bt(const bf16_t* __restrict__ A, const bf16_t* __restrict__ Bt,
                        void* __restrict__ Cv, int M, int N, int K, int Kc,
                        long sA, long sB, long sC, unsigned* __restrict__ amax) {
  __shared__ __align__(16) char lds[(BM + BN) * BK * 2];  // 32 KB
  char* ldsA = lds;
  char* ldsB = lds + BM * BK * 2;

  const int t = threadIdx.x;
  const int lane = t & 63;
  const int w = t >> 6;
  const int wm = w >> 1, wn = w & 1;
  const int quad = lane >> 4, l15 = lane & 15;
  const int m0 = blockIdx.x * BM;
  const int n0 = blockIdx.y * BN;
  const int z = blockIdx.z;
  const int b = z & 3;
  const int kz = z >> 2;

  const bf16_t* Ab = A + (size_t)b * sA + (size_t)kz * Kc;
  const bf16_t* Bb = Bt + (size_t)b * sB + (size_t)kz * Kc;

  size_t aSrc[4], bSrc[4];
#pragma unroll
  for (int i = 0; i < 4; ++i) {
    int c = i * 256 + t;
    int r = c >> 3;
    int kcs = (c & 7) ^ (r & 7);
    aSrc[i] = (size_t)(m0 + r) * K + (size_t)kcs * 8;
    bSrc[i] = (size_t)(n0 + r) * K + (size_t)kcs * 8;
  }

  f32x4 acc[4][4];
#pragma unroll
  for (int mi = 0; mi < 4; ++mi)
#pragma unroll
    for (int ni = 0; ni < 4; ++ni)
      acc[mi][ni] = f32x4{0.f, 0.f, 0.f, 0.f};

  const int aRowB = (wm * 64 + l15) * (BK * 2);
  const int bRowB = (wn * 64 + l15) * (BK * 2);
  const int xc0 = (quad ^ (lane & 7)) * 16;

  for (int k0 = 0; k0 < Kc; k0 += BK) {
#pragma unroll
    for (int i = 0; i < 4; ++i) {
      stage16(Ab + aSrc[i] + k0, ldsA + (i * 256 + t) * 16);
      stage16(Bb + bSrc[i] + k0, ldsB + (i * 256 + t) * 16);
    }
    __syncthreads();

#pragma unroll
    for (int ks = 0; ks < 2; ++ks) {
      const int xo = xc0 ^ (ks * 64);
      bf16x8 af[4], bfr[4];
#pragma unroll
      for (int mi = 0; mi < 4; ++mi)
        af[mi] = *(const bf16x8*)(ldsA + aRowB + mi * 2048 + xo);
#pragma unroll
      for (int ni = 0; ni < 4; ++ni)
        bfr[ni] = *(const bf16x8*)(ldsB + bRowB + ni * 2048 + xo);
#pragma unroll
      for (int mi = 0; mi < 4; ++mi)
#pragma unroll
        for (int ni = 0; ni < 4; ++ni)
          acc[mi][ni] = __builtin_amdgcn_mfma_f32_16x16x32_bf16(
              af[mi], bfr[ni], acc[mi][ni], 0, 0, 0);
    }
    __syncthreads();
  }

  const int mBase = m0 + wm * 64 + quad * 4;
  const int nBase = n0 + wn * 64 + l15;
  float mval = 0.f;

  if (OUT_MODE == 1) {
    bf16_t* Ct = (bf16_t*)Cv + (size_t)z * sC;
#pragma unroll
    for (int ni = 0; ni < 4; ++ni) {
      size_t colOff = (size_t)(nBase + ni * 16) * (size_t)M;
#pragma unroll
      for (int mi = 0; mi < 4; ++mi) {
        int rr = mBase + mi * 16;
        float v0 = acc[mi][ni][0], v1 = acc[mi][ni][1];
        float v2 = acc[mi][ni][2], v3 = acc[mi][ni][3];
        if (RELU) {
          v0 = fmaxf(v0, 0.f); v1 = fmaxf(v1, 0.f);
          v2 = fmaxf(v2, 0.f); v3 = fmaxf(v3, 0.f);
        }
        if (AMAX) {
          mval = fmaxf(mval, fmaxf(fmaxf(fabsf(v0), fabsf(v1)),
                                   fmaxf(fabsf(v2), fabsf(v3))));
        }
        uint2 pkv;
        pkv.x = pk2(v0, v1);
        pkv.y = pk2(v2, v3);
        *(uint2*)(Ct + colOff + rr) = pkv;
      }
    }
  } else if (OUT_MODE == 0) {
    bf16_t* C = (bf16_t*)Cv + (size_t)z * sC;
#pragma unroll
    for (int mi = 0; mi < 4; ++mi) {
#pragma unroll
      for (int j = 0; j < 4; ++j) {
        size_t rowOff = (size_t)(mBase + mi * 16 + j) * (size_t)N;
#pragma unroll
        for (int ni = 0; ni < 4; ++ni) {
          float v = acc[mi][ni][j];
          if (RELU) v = fmaxf(v, 0.f);
          if (AMAX) mval = fmaxf(mval, fabsf(v));
          C[rowOff + nBase + ni * 16] = __float2bfloat16(v);
        }
      }
    }
  } else {
    float* C = (float*)Cv + (size_t)z * sC;
#pragma unroll
    for (int mi = 0; mi < 4; ++mi) {
#pragma unroll
      for (int j = 0; j < 4; ++j) {
        size_t rowOff = (size_t)(mBase + mi * 16 + j) * (size_t)N;
#pragma unroll
        for (int ni = 0; ni < 4; ++ni) {
          float v = acc[mi][ni][j];
          if (RELU) v = fmaxf(v, 0.f);
          C[rowOff + nBase + ni * 16] = v;
        }
      }
    }
  }

  if (AMAX) block_max_commit(mval, amax);
}

// ---------------- int8 GEMM (adjacency GEMMs; R7-validated) ----------------
// BKQ=128 i8 = 128 B rows = same staging geometry as bf16 core. K-step = 64 i8
// = 4 chunks. A: AW_q (static scale 127). B: per-tensor scale mx in *slot.
// Epilogue: v = acc * mx / 127^2. Output bf16 row-major partial at z*sC.
// R4 split-K policy: minimize partial-C traffic. SK=1 (direct write) when the
// no-split grid still gives >=2 blocks/CU; else SK=2.
__global__ void gemm_i8(const int8_t* __restrict__ A, const int8_t* __restrict__ Bt,
                        bf16_t* __restrict__ C, int M, int N, int K, int Kc,
                        long sA, long sB, long sC,
                        const unsigned* __restrict__ slot) {
  __shared__ __align__(16) char lds[(BM + BN) * BKQ];  // 32 KB
  char* ldsA = lds;
  char* ldsB = lds + BM * BKQ;

  const int t = threadIdx.x;
  const int lane = t & 63;
  const int w = t >> 6;
  const int wm = w >> 1, wn = w & 1;
  const int quad = lane >> 4, l15 = lane & 15;
  const int m0 = blockIdx.x * BM;
  const int n0 = blockIdx.y * BN;
  const int z = blockIdx.z;
  const int b = z & 3;
  const int kz = z >> 2;

  const int8_t* Ab = A + (size_t)b * sA + (size_t)kz * Kc;
  const int8_t* Bb = Bt + (size_t)b * sB + (size_t)kz * Kc;

  size_t aSrc[4], bSrc[4];
#pragma unroll
  for (int i = 0; i < 4; ++i) {
    int c = i * 256 + t;
    int r = c >> 3;
    int kcs = (c & 7) ^ (r & 7);
    aSrc[i] = (size_t)(m0 + r) * K + (size_t)kcs * 16;  // 16 i8 per chunk
    bSrc[i] = (size_t)(n0 + r) * K + (size_t)kcs * 16;
  }

  i32x4 acc[4][4];
#pragma unroll
  for (int mi = 0; mi < 4; ++mi)
#pragma unroll
    for (int ni = 0; ni < 4; ++ni)
      acc[mi][ni] = i32x4{0, 0, 0, 0};

  const int aRowB = (wm * 64 + l15) * BKQ;
  const int bRowB = (wn * 64 + l15) * BKQ;
  const int xc0 = (quad ^ (lane & 7)) * 16;

  for (int k0 = 0; k0 < Kc; k0 += BKQ) {
#pragma unroll
    for (int i = 0; i < 4; ++i) {
      stage16(Ab + aSrc[i] + k0, ldsA + (i * 256 + t) * 16);
      stage16(Bb + bSrc[i] + k0, ldsB + (i * 256 + t) * 16);
    }
    __syncthreads();

#pragma unroll
    for (int ks = 0; ks < 2; ++ks) {        // two K=64 MFMA steps per BKQ=128
      const int xo = xc0 ^ (ks * 64);
      i32x4 af[4], bfr[4];
#pragma unroll
      for (int mi = 0; mi < 4; ++mi)
        af[mi] = *(const i32x4*)(ldsA + aRowB + mi * 2048 + xo);
#pragma unroll
      for (int ni = 0; ni < 4; ++ni)
        bfr[ni] = *(const i32x4*)(ldsB + bRowB + ni * 2048 + xo);
#pragma unroll
      for (int mi = 0; mi < 4; ++mi)
#pragma unroll
        for (int ni = 0; ni < 4; ++ni)
          acc[mi][ni] = __builtin_amdgcn_mfma_i32_16x16x64_i8(
              af[mi], bfr[ni], acc[mi][ni], 0, 0, 0);
    }
    __syncthreads();
  }

  const float mx = fmaxf(__uint_as_float(*slot), 1e-20f);
  const float sc = mx * (1.0f / 16129.0f);  // / (127*127)

  const int mBase = m0 + wm * 64 + quad * 4;
  const int nBase = n0 + wn * 64 + l15;
  bf16_t* Cb = C + (size_t)z * sC;
#pragma unroll
  for (int mi = 0; mi < 4; ++mi) {
#pragma unroll
    for (int j = 0; j < 4; ++j) {
      size_t rowOff = (size_t)(mBase + mi * 16 + j) * (size_t)N;
#pragma unroll
      for (int ni = 0; ni < 4; ++ni)
        Cb[rowOff + nBase + ni * 16] = __float2bfloat16((float)acc[mi][ni][j] * sc);
    }
  }
}

// Sum SK bf16 partial chunks (stride tot) in fp32; write bf16 or f32.
// AMAX: fuse per-tensor absmax of the summed outputs (block max -> 1 atomic).
// CONTRACT: (tot/8) % (gridDim.x * blockDim.x * 2) == 0 at every call site.
template <int SK, bool F32OUT, bool AMAX>
__global__ void reduce_k(const bf16_t* __restrict__ pp, void* __restrict__ out,
                         size_t tot, unsigned* __restrict__ amax) {
  const int bs = blockDim.x;
  size_t base = (size_t)blockIdx.x * bs * 2 + threadIdx.x;  // 8-elem group idx
  bf16x8 v[2][SK];
#pragma unroll
  for (int u = 0; u < 2; ++u) {
    size_t g = base + (size_t)u * bs;
#pragma unroll
    for (int kz = 0; kz < SK; ++kz)
      v[u][kz] = *(const bf16x8*)(pp + (size_t)kz * tot + g * 8);
  }
  float mval = 0.f;
#pragma unroll
  for (int u = 0; u < 2; ++u) {
    size_t g = base + (size_t)u * bs;
    float s[8];
#pragma unroll
    for (int j = 0; j < 8; ++j) s[j] = 0.f;
#pragma unroll
    for (int kz = 0; kz < SK; ++kz)
#pragma unroll
      for (int j = 0; j < 8; ++j) s[j] += (float)v[u][kz][j];
    if (AMAX) {
#pragma unroll
      for (int j = 0; j < 8; ++j) mval = fmaxf(mval, fabsf(s[j]));
    }
    if (F32OUT) {
      float* o = (float*)out + g * 8;
      float4 r0{s[0], s[1], s[2], s[3]};
      float4 r1{s[4], s[5], s[6], s[7]};
      ((float4*)o)[0] = r0;
      ((float4*)o)[1] = r1;
    } else {
      uint4 r;
      r.x = pk2(s[0], s[1]);
      r.y = pk2(s[2], s[3]);
      r.z = pk2(s[4], s[5]);
      r.w = pk2(s[6], s[7]);
      *(uint4*)((bf16_t*)out + g * 8) = r;
    }
  }
  if (AMAX) block_max_commit(mval, amax);
}

// ---------------- fused prep kernel (one launch, partitioned grid) ----------
// Segment A (blocks [0,512)):          absmax(x) -> SX  (grid-stride, 2 iters)
// Segment B (blocks [512,512+3584)):   W1/W2/W3 transpose+cast. 3584*256 =
//                                      917504 = n1+n2+n3 EXACTLY (R2 bug: 5120
//                                      here overran W3T by ~1MB, clobbering SC).
// Segment C (blocks [4096,4096+16384)): AW_q = round(adj*S*127), 1 float4/thr.
//   R7 CONFIRMED: nontemporal loads on adj/S dropped prep out of the top-5
//   (was 59us; now <42us) -- the 134MB read-once stream was polluting the
//   cache hierarchy. KEEP nt. AWQ store stays cached (re-read 3x by gemms).
// SX/SH1/SST3 slots are zeroed by a hipMemsetAsync node BEFORE this kernel.
#define PREP_AMX 512
#define PREP_C3  3584   // (256*512 + 512*1024 + 1024*256) / 256  == 3584
#define PREP_MC  16384  // (4096*4096/4) / 256

__global__ void prep_kernel(const float* __restrict__ adj, const float* __restrict__ S,
                            int8_t* __restrict__ o,
                            const float* __restrict__ x, size_t n4x,
                            unsigned* __restrict__ SX,
                            const float* __restrict__ W1, const float* __restrict__ W2,
                            const float* __restrict__ W3, bf16_t* __restrict__ W1T,
                            bf16_t* __restrict__ W2T, bf16_t* __restrict__ W3T) {
  const int bid = blockIdx.x;
  const int tid = threadIdx.x;

  if (bid < PREP_AMX) {
    // absmax over x (f32), 4 float4 loads in flight per iter
    size_t base = (size_t)bid * (256 * 4) + tid;
    const size_t stride = (size_t)PREP_AMX * 256 * 4;
    float m = 0.f;
    for (; base + 3 * 256 < n4x; base += stride) {
      float4 v[4];
#pragma unroll
      for (int j = 0; j < 4; ++j) v[j] = ((const float4*)x)[base + (size_t)j * 256];
#pragma unroll
      for (int j = 0; j < 4; ++j)
        m = fmaxf(m, fmaxf(fmaxf(fabsf(v[j].x), fabsf(v[j].y)),
                           fmaxf(fabsf(v[j].z), fabsf(v[j].w))));
    }
    block_max_commit(m, SX);
  } else if (bid < PREP_AMX + PREP_C3) {
    const int n1 = 256 * 512;
    const int n2 = 512 * 1024;
    const int n3 = 1024 * 256;
    int idx = (bid - PREP_AMX) * 256 + tid;
    if (idx < n1) {
      int K = 256, H = 512;
      int h = idx / K, k = idx - h * K;
      W1T[idx] = __float2bfloat16(W1[(size_t)k * H + h]);
    } else if (idx < n1 + n2) {
      int i = idx - n1;
      int K = 512, H = 1024;
      int h = i / K, k = i - h * K;
      W2T[i] = __float2bfloat16(W2[(size_t)k * H + h]);
    } else if (idx < n1 + n2 + n3) {
      int i = idx - n1 - n2;
      int K = 1024, H = 256;
      int h = i / K, k = i - h * K;
      W3T[i] = __float2bfloat16(W3[(size_t)k * H + h]);
    }
  } else {
    int i = (bid - PREP_AMX - PREP_C3) * 256 + tid;
    f32x4 av = __builtin_nontemporal_load((const f32x4*)adj + i);
    f32x4 sv = __builtin_nontemporal_load((const f32x4*)S + i);
    float v0 = av[0] * sv[0] * 127.f, v1 = av[1] * sv[1] * 127.f;
    float v2 = av[2] * sv[2] * 127.f, v3 = av[3] * sv[3] * 127.f;
    int q0 = (int)rintf(fminf(fmaxf(v0, -127.f), 127.f));
    int q1 = (int)rintf(fminf(fmaxf(v1, -127.f), 127.f));
    int q2 = (int)rintf(fminf(fmaxf(v2, -127.f), 127.f));
    int q3 = (int)rintf(fminf(fmaxf(v3, -127.f), 127.f));
    unsigned p = (unsigned)(q0 & 255) | ((unsigned)(q1 & 255) << 8) |
                 ((unsigned)(q2 & 255) << 16) | ((unsigned)(q3 & 255) << 24);
    ((unsigned*)o)[i] = p;
  }
}

// x [B][4096][256] f32 -> xt [B][256][4096] i8 (scale 127/mx from slot)
__global__ void transpose_quant_x(const float* __restrict__ x, int8_t* __restrict__ xt,
                                  const unsigned* __restrict__ slot) {
  __shared__ float tile[32][33];
  const int N = 4096, F = 256;
  float qs = 127.0f / fmaxf(__uint_as_float(*slot), 1e-20f);
  int n0 = blockIdx.x * 32, f0 = blockIdx.y * 32, b = blockIdx.z;
  const float* xb = x + (size_t)b * N * F;
  int8_t* xtb = xt + (size_t)b * N * F;
  int tx = threadIdx.x & 31, ty = threadIdx.x >> 5;  // 32 x 8
#pragma unroll
  for (int i = 0; i < 32; i += 8)
    tile[ty + i][tx] = xb[(size_t)(n0 + ty + i) * F + f0 + tx];
  __syncthreads();
#pragma unroll
  for (int i = 0; i < 32; i += 8) {
    float v = tile[tx][ty + i] * qs;
    xtb[(size_t)(f0 + ty + i) * N + n0 + tx] =
        (int8_t)(int)rintf(fminf(fmaxf(v, -127.f), 127.f));
  }
}

// bf16 -> i8 with scale 127/mx from slot; 4 groups of 8 elems per thread.
// CONTRACT: n8 % (gridDim.x * blockDim.x * 4) == 0 at every call site.
__global__ void quant8(const bf16_t* __restrict__ in, int8_t* __restrict__ out,
                       const unsigned* __restrict__ slot, size_t n8) {
  const int bs = blockDim.x;
  size_t base = (size_t)blockIdx.x * bs * 4 + threadIdx.x;
  float qs = 127.0f / fmaxf(__uint_as_float(*slot), 1e-20f);
  bf16x8 v[4];
#pragma unroll
  for (int j = 0; j < 4; ++j)
    v[j] = *(const bf16x8*)(in + (base + (size_t)j * bs) * 8);
#pragma unroll
  for (int j = 0; j < 4; ++j) {
    unsigned lo = 0, hi = 0;
#pragma unroll
    for (int e = 0; e < 4; ++e) {
      int q = (int)rintf(fminf(fmaxf((float)v[j][e] * qs, -127.f), 127.f));
      lo |= (unsigned)(q & 255) << (8 * e);
    }
#pragma unroll
    for (int e = 0; e < 4; ++e) {
      int q = (int)rintf(fminf(fmaxf((float)v[j][4 + e] * qs, -127.f), 127.f));
      hi |= (unsigned)(q & 255) << (8 * e);
    }
    uint2 r{lo, hi};
    ((uint2*)out)[base + (size_t)j * bs] = r;
  }
}

extern "C" void kernel_launch(void* const* d_in, const int* in_sizes, int n_in,
                              void* d_out, int out_size, void* d_ws, size_t ws_size,
                              hipStream_t stream) {
  const float* x   = (const float*)d_in[0];  // [4, 4096, 256]
  const float* adj = (const float*)d_in[1];  // [4096, 4096]
  const float* S   = (const float*)d_in[2];  // [4096, 4096]
  const float* W1  = (const float*)d_in[3];  // [256, 512]
  const float* W2  = (const float*)d_in[4];  // [512, 1024]
  const float* W3  = (const float*)d_in[5];  // [1024, 256]

  const int N = 4096, F = 256, H1 = 512, H2 = 1024, NC = 256, B = 4;

  // Chain (adjacency GEMMs i8, support GEMMs bf16), R7 workspace (~98.5 MiB):
  char* ws = (char*)d_ws;
  int8_t* AWQ  = (int8_t*)ws; ws += (size_t)N * N;           // 16.8 MB
  bf16_t* SCR  = (bf16_t*)ws; ws += (size_t)B * N * H2 * 2;  // 33.5 MB partials/H2B
  int8_t* XQT  = (int8_t*)ws; ws += (size_t)B * F * N;       //  4.2 MB
  bf16_t* BufY = (bf16_t*)ws; ws += (size_t)B * N * H1 * 2;  // 16.8 MB G1/G2/ST3T
  bf16_t* BufZ = (bf16_t*)ws; ws += (size_t)B * N * H1 * 2;  // 16.8 MB H1T/st3 partials
  int8_t* QS   = (int8_t*)ws; ws += (size_t)B * H1 * N;      //  8.4 MB H1Q/ST3Q
  bf16_t* W1T  = (bf16_t*)ws; ws += (size_t)F * H1 * 2;
  bf16_t* W2T  = (bf16_t*)ws; ws += (size_t)H1 * H2 * 2;
  bf16_t* W3T  = (bf16_t*)ws; ws += (size_t)H2 * NC * 2;
  unsigned* SC = (unsigned*)ws;                              // 3 scale slots
  unsigned* SX = SC, *SH1 = SC + 1, *SST3 = SC + 2;

  bf16_t* G1 = BufY, *G2 = BufY, *ST3T = BufY;
  bf16_t* H1T = BufZ;
  bf16_t* H2B = SCR;
  int8_t* H1Q = QS, *ST3Q = QS;

  dim3 blk(THREADS);

  // prep: zero the 3 scale slots (graph-legal memset node), then one fused
  // kernel: absmax(x) | weight cast3 | AW_q quantize (nt loads).
  (void)hipMemsetAsync(SC, 0, 3 * sizeof(unsigned), stream);
  prep_kernel<<<PREP_AMX + PREP_C3 + PREP_MC, 256, 0, stream>>>(
      adj, S, AWQ, x, (size_t)B * N * F / 4, SX, W1, W2, W3, W1T, W2T, W3T);
  transpose_quant_x<<<dim3(N / 32, F / 32, B), 256, 0, stream>>>(x, XQT, SX);

  // L1: g1 = AWq @ xq, SK=2 -> SCR, reduce -> G1.  Grid (32,2,8) = 512 blocks.
  gemm_i8<<<dim3(N / BM, F / BN, B * 2), blk, 0, stream>>>(
      AWQ, XQT, SCR, N, F, N, N / 2, 0, (long)F * N, (long)N * F, SX);
  // groups = B*N*F/8 = 524,288 ; 1024*256*2 = 524,288 -> exact.
  reduce_k<2, false, false><<<1024, 256, 0, stream>>>(SCR, G1, (size_t)B * N * F, nullptr);
  //     h1^T = relu(g1 @ W1)^T -> H1T, absmax fused into epilogue -> SH1
  gemm_bt<1, true, true><<<dim3(N / BM, H1 / BN, B), blk, 0, stream>>>(
      G1, W1T, H1T, N, H1, F, F, (long)N * F, 0, (long)H1 * N, SH1);
  // n8 = 1,048,576 ; 1024*256*4 = 1,048,576 -> exact single shot.
  quant8<<<1024, 256, 0, stream>>>(H1T, H1Q, SH1, (size_t)B * H1 * N / 8);

  // L2: g2 = AWq @ h1q, NO split-K (direct write -> G2). Grid (32,4,4) = 512.
  gemm_i8<<<dim3(N / BM, H1 / BN, B), blk, 0, stream>>>(
      AWQ, H1Q, G2, N, H1, N, N, 0, (long)H1 * N, (long)N * H1, SH1);
  //     h2 = relu(g2 @ W2) -> H2B (SCR).  Grid (32,8,4) = 1024.
  gemm_bt<0, true, false><<<dim3(N / BM, H2 / BN, B), blk, 0, stream>>>(
      G2, W2T, H2B, N, H2, H1, H1, (long)N * H1, 0, (long)N * H2, nullptr);

  // L3: st3^T = (h2 @ W3)^T, SK=2 -> partials BufZ, reduce+absmax -> ST3T/SST3
  gemm_bt<1, false, false><<<dim3(N / BM, NC / BN, B * 2), blk, 0, stream>>>(
      H2B, W3T, BufZ, N, NC, H2, H2 / 2, (long)N * H2, 0, (long)NC * N, nullptr);
  // groups = 524,288 -> 1024 blocks exact.
  reduce_k<2, false, true><<<1024, 256, 0, stream>>>(BufZ, ST3T, (size_t)B * NC * N, SST3);
  // n8 = 524,288 ; 512*256*4 = 524,288 -> exact single shot.
  quant8<<<512, 256, 0, stream>>>(ST3T, ST3Q, SST3, (size_t)B * NC * N / 8);
  //     out = AWq @ st3q, SK=2 -> partials SCR, reduce f32 -> d_out
  gemm_i8<<<dim3(N / BM, NC / BN, B * 2), blk, 0, stream>>>(
      AWQ, ST3Q, SCR, N, NC, N, N / 2, 0, (long)NC * N, (long)N * NC, SST3);
  // groups = 524,288 -> 1024 blocks exact.
  reduce_k<2, true, false><<<1024, 256, 0, stream>>>(SCR, d_out, (size_t)B * N * NC, nullptr);
}

// Round 9
// 336.787 us; speedup vs baseline: 1.0308x; 1.0098x over previous
//
#include <hip/hip_runtime.h>
#include <hip/hip_bf16.h>
#include <stdint.h>
#include <stddef.h>

typedef __bf16 bf16x8 __attribute__((ext_vector_type(8)));
typedef float f32x4 __attribute__((ext_vector_type(4)));
typedef int i32x4 __attribute__((ext_vector_type(4)));
typedef __hip_bfloat16 bf16_t;

#define BM 128
#define BN 128
#define BK 64      // bf16 elements per K-tile (128 B rows)
#define BKQ 128    // i8 elements per K-tile (128 B rows -- same geometry)
#define THREADS 256

// async global->LDS, 16B per lane. LDS dest must be wave-uniform-base + lane*16.
__device__ __forceinline__ void stage16(const void* g, void* l) {
  __builtin_amdgcn_global_load_lds(
      (const __attribute__((address_space(1))) uint32_t*)g,
      (__attribute__((address_space(3))) uint32_t*)l, 16, 0, 0);
}

__device__ __forceinline__ unsigned pk2(float x, float y) {
  bf16_t a = __float2bfloat16(x);
  bf16_t b = __float2bfloat16(y);
  unsigned short ua = *(unsigned short*)&a;
  unsigned short ub = *(unsigned short*)&b;
  return (unsigned)ua | ((unsigned)ub << 16);
}

// R8 NOTE: XCD chunk swizzle removed (R7 A/B: small loss on gemms, no win).
// R9 NOTE: gemm_i8 is explicitly double-buffered (see kernel comment); gemm_bt
// stays single-buffered because its L2b/L3a call sites run 4 blocks/CU, which
// 64KB LDS would halve.

// ---------------- hierarchical absmax commit (1 atomic per BLOCK) ----------
// R7 lesson: WAVE-level atomics to one address serialize (~12ns each across
// XCDs); 8192 of them = 97us. Block-level (512-1024 staggered) is ~free.
__device__ __forceinline__ void block_max_commit(float m, unsigned* slot) {
  __shared__ float red[4];
#pragma unroll
  for (int off = 32; off > 0; off >>= 1)
    m = fmaxf(m, __shfl_xor(m, off, 64));
  if ((threadIdx.x & 63) == 0) red[threadIdx.x >> 6] = m;
  __syncthreads();
  if (threadIdx.x == 0) {
    float mm = fmaxf(fmaxf(red[0], red[1]), fmaxf(red[2], red[3]));
    atomicMax(slot, __float_as_uint(mm));
  }
}

// ---------------- bf16 GEMM (R3/R6-verified core; support GEMMs) -------------
// C = A @ Bt^T. A:[M,K] row-major bf16 (row stride K, extent Kc). Bt:[N,K].
// OUT_MODE 0: bf16 row-major [M,N]; 1: bf16 transposed [N,M]; 2: f32 row-major.
// blockIdx.z = kz*4 + b (B=4). Output chunk at z*sC.
// AMAX: fuse per-tensor absmax of outputs (block max -> 1 atomic); requires
// full-K single pass (no split-K) at the call site. Max is over pre-bf16-round
// f32 values; quant8 clamps to +-127 pre-rint so the <=0.4% ULP gap is benign.
// DO NOT MODIFY staging/LDS scheme (R4: 32-row fragments -> 1.7e7 conflicts).
template <int OUT_MODE, bool RELU, bool AMAX>
__global__ void gemm_bt(const bf16_t* __restrict__ A, const bf16_t* __restrict__ Bt,
                        void* __restrict__ Cv, int M, int N, int K, int Kc,
                        long sA, long sB, long sC, unsigned* __restrict__ amax) {
  __shared__ __align__(16) char lds[(BM + BN) * BK * 2];  // 32 KB
  char* ldsA = lds;
  char* ldsB = lds + BM * BK * 2;

  const int t = threadIdx.x;
  const int lane = t & 63;
  const int w = t >> 6;
  const int wm = w >> 1, wn = w & 1;
  const int quad = lane >> 4, l15 = lane & 15;
  const int m0 = blockIdx.x * BM;
  const int n0 = blockIdx.y * BN;
  const int z = blockIdx.z;
  const int b = z & 3;
  const int kz = z >> 2;

  const bf16_t* Ab = A + (size_t)b * sA + (size_t)kz * Kc;
  const bf16_t* Bb = Bt + (size_t)b * sB + (size_t)kz * Kc;

  size_t aSrc[4], bSrc[4];
#pragma unroll
  for (int i = 0; i < 4; ++i) {
    int c = i * 256 + t;
    int r = c >> 3;
    int kcs = (c & 7) ^ (r & 7);
    aSrc[i] = (size_t)(m0 + r) * K + (size_t)kcs * 8;
    bSrc[i] = (size_t)(n0 + r) * K + (size_t)kcs * 8;
  }

  f32x4 acc[4][4];
#pragma unroll
  for (int mi = 0; mi < 4; ++mi)
#pragma unroll
    for (int ni = 0; ni < 4; ++ni)
      acc[mi][ni] = f32x4{0.f, 0.f, 0.f, 0.f};

  const int aRowB = (wm * 64 + l15) * (BK * 2);
  const int bRowB = (wn * 64 + l15) * (BK * 2);
  const int xc0 = (quad ^ (lane & 7)) * 16;

  for (int k0 = 0; k0 < Kc; k0 += BK) {
#pragma unroll
    for (int i = 0; i < 4; ++i) {
      stage16(Ab + aSrc[i] + k0, ldsA + (i * 256 + t) * 16);
      stage16(Bb + bSrc[i] + k0, ldsB + (i * 256 + t) * 16);
    }
    __syncthreads();

#pragma unroll
    for (int ks = 0; ks < 2; ++ks) {
      const int xo = xc0 ^ (ks * 64);
      bf16x8 af[4], bfr[4];
#pragma unroll
      for (int mi = 0; mi < 4; ++mi)
        af[mi] = *(const bf16x8*)(ldsA + aRowB + mi * 2048 + xo);
#pragma unroll
      for (int ni = 0; ni < 4; ++ni)
        bfr[ni] = *(const bf16x8*)(ldsB + bRowB + ni * 2048 + xo);
#pragma unroll
      for (int mi = 0; mi < 4; ++mi)
#pragma unroll
        for (int ni = 0; ni < 4; ++ni)
          acc[mi][ni] = __builtin_amdgcn_mfma_f32_16x16x32_bf16(
              af[mi], bfr[ni], acc[mi][ni], 0, 0, 0);
    }
    __syncthreads();
  }

  const int mBase = m0 + wm * 64 + quad * 4;
  const int nBase = n0 + wn * 64 + l15;
  float mval = 0.f;

  if (OUT_MODE == 1) {
    bf16_t* Ct = (bf16_t*)Cv + (size_t)z * sC;
#pragma unroll
    for (int ni = 0; ni < 4; ++ni) {
      size_t colOff = (size_t)(nBase + ni * 16) * (size_t)M;
#pragma unroll
      for (int mi = 0; mi < 4; ++mi) {
        int rr = mBase + mi * 16;
        float v0 = acc[mi][ni][0], v1 = acc[mi][ni][1];
        float v2 = acc[mi][ni][2], v3 = acc[mi][ni][3];
        if (RELU) {
          v0 = fmaxf(v0, 0.f); v1 = fmaxf(v1, 0.f);
          v2 = fmaxf(v2, 0.f); v3 = fmaxf(v3, 0.f);
        }
        if (AMAX) {
          mval = fmaxf(mval, fmaxf(fmaxf(fabsf(v0), fabsf(v1)),
                                   fmaxf(fabsf(v2), fabsf(v3))));
        }
        uint2 pkv;
        pkv.x = pk2(v0, v1);
        pkv.y = pk2(v2, v3);
        *(uint2*)(Ct + colOff + rr) = pkv;
      }
    }
  } else if (OUT_MODE == 0) {
    bf16_t* C = (bf16_t*)Cv + (size_t)z * sC;
#pragma unroll
    for (int mi = 0; mi < 4; ++mi) {
#pragma unroll
      for (int j = 0; j < 4; ++j) {
        size_t rowOff = (size_t)(mBase + mi * 16 + j) * (size_t)N;
#pragma unroll
        for (int ni = 0; ni < 4; ++ni) {
          float v = acc[mi][ni][j];
          if (RELU) v = fmaxf(v, 0.f);
          if (AMAX) mval = fmaxf(mval, fabsf(v));
          C[rowOff + nBase + ni * 16] = __float2bfloat16(v);
        }
      }
    }
  } else {
    float* C = (float*)Cv + (size_t)z * sC;
#pragma unroll
    for (int mi = 0; mi < 4; ++mi) {
#pragma unroll
      for (int j = 0; j < 4; ++j) {
        size_t rowOff = (size_t)(mBase + mi * 16 + j) * (size_t)N;
#pragma unroll
        for (int ni = 0; ni < 4; ++ni) {
          float v = acc[mi][ni][j];
          if (RELU) v = fmaxf(v, 0.f);
          C[rowOff + nBase + ni * 16] = v;
        }
      }
    }
  }

  if (AMAX) block_max_commit(mval, amax);
}

// ---------------- int8 GEMM (adjacency GEMMs; R7-validated core) -------------
// BKQ=128 i8 = 128 B rows. A: AW_q (static scale 127). B: per-tensor scale mx
// in *slot. Epilogue: v = acc * mx / 127^2. Output bf16 row-major at z*sC.
// R9: EXPLICIT LDS DOUBLE-BUFFER (T3-minimum 2-phase). All three i8 call sites
// are grid-limited to 2 blocks/CU (512-block grids), so the 1-phase
// stage->barrier->compute->barrier loop exposed full load latency at every
// K-step (R8 counters: MfmaUtil 30%, occ 17.5%). Dbuf issues tile t+1's
// global_load_lds BEFORE computing tile t and needs only ONE barrier per
// K-step. LDS 64KB: 2 blocks x 64KB = 128 <= 160KB -> occupancy unchanged.
__global__ void gemm_i8(const int8_t* __restrict__ A, const int8_t* __restrict__ Bt,
                        bf16_t* __restrict__ C, int M, int N, int K, int Kc,
                        long sA, long sB, long sC,
                        const unsigned* __restrict__ slot) {
  __shared__ __align__(16) char lds[2 * (BM + BN) * BKQ];  // 64 KB (2 buffers)
  const int BUF = (BM + BN) * BKQ;                          // 32768

  const int t = threadIdx.x;
  const int lane = t & 63;
  const int w = t >> 6;
  const int wm = w >> 1, wn = w & 1;
  const int quad = lane >> 4, l15 = lane & 15;
  const int m0 = blockIdx.x * BM;
  const int n0 = blockIdx.y * BN;
  const int z = blockIdx.z;
  const int b = z & 3;
  const int kz = z >> 2;

  const int8_t* Ab = A + (size_t)b * sA + (size_t)kz * Kc;
  const int8_t* Bb = Bt + (size_t)b * sB + (size_t)kz * Kc;

  size_t aSrc[4], bSrc[4];
#pragma unroll
  for (int i = 0; i < 4; ++i) {
    int c = i * 256 + t;
    int r = c >> 3;
    int kcs = (c & 7) ^ (r & 7);
    aSrc[i] = (size_t)(m0 + r) * K + (size_t)kcs * 16;  // 16 i8 per chunk
    bSrc[i] = (size_t)(n0 + r) * K + (size_t)kcs * 16;
  }

  i32x4 acc[4][4];
#pragma unroll
  for (int mi = 0; mi < 4; ++mi)
#pragma unroll
    for (int ni = 0; ni < 4; ++ni)
      acc[mi][ni] = i32x4{0, 0, 0, 0};

  const int aRowB = (wm * 64 + l15) * BKQ;
  const int bRowB = (wn * 64 + l15) * BKQ;
  const int xc0 = (quad ^ (lane & 7)) * 16;

  // prologue: stage K-tile 0 into buffer 0
#pragma unroll
  for (int i = 0; i < 4; ++i) {
    stage16(Ab + aSrc[i], lds + (i * 256 + t) * 16);
    stage16(Bb + bSrc[i], lds + BM * BKQ + (i * 256 + t) * 16);
  }
  __syncthreads();

  int cur = 0;
  for (int k0 = 0; k0 < Kc; k0 += BKQ) {
    const int nxt = k0 + BKQ;
    if (nxt < Kc) {  // wave-uniform branch
      char* dst = lds + (cur ^ 1) * BUF;
#pragma unroll
      for (int i = 0; i < 4; ++i) {
        stage16(Ab + aSrc[i] + nxt, dst + (i * 256 + t) * 16);
        stage16(Bb + bSrc[i] + nxt, dst + BM * BKQ + (i * 256 + t) * 16);
      }
    }
    const char* ldsA = lds + cur * BUF;
    const char* ldsB = ldsA + BM * BKQ;

#pragma unroll
    for (int ks = 0; ks < 2; ++ks) {        // two K=64 MFMA steps per BKQ=128
      const int xo = xc0 ^ (ks * 64);
      i32x4 af[4], bfr[4];
#pragma unroll
      for (int mi = 0; mi < 4; ++mi)
        af[mi] = *(const i32x4*)(ldsA + aRowB + mi * 2048 + xo);
#pragma unroll
      for (int ni = 0; ni < 4; ++ni)
        bfr[ni] = *(const i32x4*)(ldsB + bRowB + ni * 2048 + xo);
#pragma unroll
      for (int mi = 0; mi < 4; ++mi)
#pragma unroll
        for (int ni = 0; ni < 4; ++ni)
          acc[mi][ni] = __builtin_amdgcn_mfma_i32_16x16x64_i8(
              af[mi], bfr[ni], acc[mi][ni], 0, 0, 0);
    }
    __syncthreads();   // one barrier per K-step: drains t+1 loads, guards reuse
    cur ^= 1;
  }

  const float mx = fmaxf(__uint_as_float(*slot), 1e-20f);
  const float sc = mx * (1.0f / 16129.0f);  // / (127*127)

  const int mBase = m0 + wm * 64 + quad * 4;
  const int nBase = n0 + wn * 64 + l15;
  bf16_t* Cb = C + (size_t)z * sC;
#pragma unroll
  for (int mi = 0; mi < 4; ++mi) {
#pragma unroll
    for (int j = 0; j < 4; ++j) {
      size_t rowOff = (size_t)(mBase + mi * 16 + j) * (size_t)N;
#pragma unroll
      for (int ni = 0; ni < 4; ++ni)
        Cb[rowOff + nBase + ni * 16] = __float2bfloat16((float)acc[mi][ni][j] * sc);
    }
  }
}

// Sum SK bf16 partial chunks (stride tot) in fp32; write bf16 or f32.
// AMAX: fuse per-tensor absmax of the summed outputs (block max -> 1 atomic).
// CONTRACT: (tot/8) % (gridDim.x * blockDim.x * 2) == 0 at every call site.
template <int SK, bool F32OUT, bool AMAX>
__global__ void reduce_k(const bf16_t* __restrict__ pp, void* __restrict__ out,
                         size_t tot, unsigned* __restrict__ amax) {
  const int bs = blockDim.x;
  size_t base = (size_t)blockIdx.x * bs * 2 + threadIdx.x;  // 8-elem group idx
  bf16x8 v[2][SK];
#pragma unroll
  for (int u = 0; u < 2; ++u) {
    size_t g = base + (size_t)u * bs;
#pragma unroll
    for (int kz = 0; kz < SK; ++kz)
      v[u][kz] = *(const bf16x8*)(pp + (size_t)kz * tot + g * 8);
  }
  float mval = 0.f;
#pragma unroll
  for (int u = 0; u < 2; ++u) {
    size_t g = base + (size_t)u * bs;
    float s[8];
#pragma unroll
    for (int j = 0; j < 8; ++j) s[j] = 0.f;
#pragma unroll
    for (int kz = 0; kz < SK; ++kz)
#pragma unroll
      for (int j = 0; j < 8; ++j) s[j] += (float)v[u][kz][j];
    if (AMAX) {
#pragma unroll
      for (int j = 0; j < 8; ++j) mval = fmaxf(mval, fabsf(s[j]));
    }
    if (F32OUT) {
      float* o = (float*)out + g * 8;
      float4 r0{s[0], s[1], s[2], s[3]};
      float4 r1{s[4], s[5], s[6], s[7]};
      ((float4*)o)[0] = r0;
      ((float4*)o)[1] = r1;
    } else {
      uint4 r;
      r.x = pk2(s[0], s[1]);
      r.y = pk2(s[2], s[3]);
      r.z = pk2(s[4], s[5]);
      r.w = pk2(s[6], s[7]);
      *(uint4*)((bf16_t*)out + g * 8) = r;
    }
  }
  if (AMAX) block_max_commit(mval, amax);
}

// ---------------- fused prep kernel (one launch, partitioned grid) ----------
// Segment A (blocks [0,512)):          absmax(x) -> SX  (grid-stride, 2 iters)
// Segment B (blocks [512,512+3584)):   W1/W2/W3 transpose+cast. 3584*256 =
//                                      917504 = n1+n2+n3 EXACTLY (R2 bug: 5120
//                                      here overran W3T by ~1MB, clobbering SC).
// Segment C (blocks [4096,4096+16384)): AW_q = round(adj*S*127), 1 float4/thr.
//   R7 CONFIRMED: nontemporal loads on adj/S dropped prep out of the top-5
//   (was 59us; now <42us) -- the 134MB read-once stream was polluting the
//   cache hierarchy. KEEP nt. AWQ store stays cached (re-read 3x by gemms).
// SX/SH1/SST3 slots are zeroed by a hipMemsetAsync node BEFORE this kernel.
#define PREP_AMX 512
#define PREP_C3  3584   // (256*512 + 512*1024 + 1024*256) / 256  == 3584
#define PREP_MC  16384  // (4096*4096/4) / 256

__global__ void prep_kernel(const float* __restrict__ adj, const float* __restrict__ S,
                            int8_t* __restrict__ o,
                            const float* __restrict__ x, size_t n4x,
                            unsigned* __restrict__ SX,
                            const float* __restrict__ W1, const float* __restrict__ W2,
                            const float* __restrict__ W3, bf16_t* __restrict__ W1T,
                            bf16_t* __restrict__ W2T, bf16_t* __restrict__ W3T) {
  const int bid = blockIdx.x;
  const int tid = threadIdx.x;

  if (bid < PREP_AMX) {
    // absmax over x (f32), 4 float4 loads in flight per iter
    size_t base = (size_t)bid * (256 * 4) + tid;
    const size_t stride = (size_t)PREP_AMX * 256 * 4;
    float m = 0.f;
    for (; base + 3 * 256 < n4x; base += stride) {
      float4 v[4];
#pragma unroll
      for (int j = 0; j < 4; ++j) v[j] = ((const float4*)x)[base + (size_t)j * 256];
#pragma unroll
      for (int j = 0; j < 4; ++j)
        m = fmaxf(m, fmaxf(fmaxf(fabsf(v[j].x), fabsf(v[j].y)),
                           fmaxf(fabsf(v[j].z), fabsf(v[j].w))));
    }
    block_max_commit(m, SX);
  } else if (bid < PREP_AMX + PREP_C3) {
    const int n1 = 256 * 512;
    const int n2 = 512 * 1024;
    const int n3 = 1024 * 256;
    int idx = (bid - PREP_AMX) * 256 + tid;
    if (idx < n1) {
      int K = 256, H = 512;
      int h = idx / K, k = idx - h * K;
      W1T[idx] = __float2bfloat16(W1[(size_t)k * H + h]);
    } else if (idx < n1 + n2) {
      int i = idx - n1;
      int K = 512, H = 1024;
      int h = i / K, k = i - h * K;
      W2T[i] = __float2bfloat16(W2[(size_t)k * H + h]);
    } else if (idx < n1 + n2 + n3) {
      int i = idx - n1 - n2;
      int K = 1024, H = 256;
      int h = i / K, k = i - h * K;
      W3T[i] = __float2bfloat16(W3[(size_t)k * H + h]);
    }
  } else {
    int i = (bid - PREP_AMX - PREP_C3) * 256 + tid;
    f32x4 av = __builtin_nontemporal_load((const f32x4*)adj + i);
    f32x4 sv = __builtin_nontemporal_load((const f32x4*)S + i);
    float v0 = av[0] * sv[0] * 127.f, v1 = av[1] * sv[1] * 127.f;
    float v2 = av[2] * sv[2] * 127.f, v3 = av[3] * sv[3] * 127.f;
    int q0 = (int)rintf(fminf(fmaxf(v0, -127.f), 127.f));
    int q1 = (int)rintf(fminf(fmaxf(v1, -127.f), 127.f));
    int q2 = (int)rintf(fminf(fmaxf(v2, -127.f), 127.f));
    int q3 = (int)rintf(fminf(fmaxf(v3, -127.f), 127.f));
    unsigned p = (unsigned)(q0 & 255) | ((unsigned)(q1 & 255) << 8) |
                 ((unsigned)(q2 & 255) << 16) | ((unsigned)(q3 & 255) << 24);
    ((unsigned*)o)[i] = p;
  }
}

// x [B][4096][256] f32 -> xt [B][256][4096] i8 (scale 127/mx from slot)
__global__ void transpose_quant_x(const float* __restrict__ x, int8_t* __restrict__ xt,
                                  const unsigned* __restrict__ slot) {
  __shared__ float tile[32][33];
  const int N = 4096, F = 256;
  float qs = 127.0f / fmaxf(__uint_as_float(*slot), 1e-20f);
  int n0 = blockIdx.x * 32, f0 = blockIdx.y * 32, b = blockIdx.z;
  const float* xb = x + (size_t)b * N * F;
  int8_t* xtb = xt + (size_t)b * N * F;
  int tx = threadIdx.x & 31, ty = threadIdx.x >> 5;  // 32 x 8
#pragma unroll
  for (int i = 0; i < 32; i += 8)
    tile[ty + i][tx] = xb[(size_t)(n0 + ty + i) * F + f0 + tx];
  __syncthreads();
#pragma unroll
  for (int i = 0; i < 32; i += 8) {
    float v = tile[tx][ty + i] * qs;
    xtb[(size_t)(f0 + ty + i) * N + n0 + tx] =
        (int8_t)(int)rintf(fminf(fmaxf(v, -127.f), 127.f));
  }
}

// bf16 -> i8 with scale 127/mx from slot; 4 groups of 8 elems per thread.
// CONTRACT: n8 % (gridDim.x * blockDim.x * 4) == 0 at every call site.
__global__ void quant8(const bf16_t* __restrict__ in, int8_t* __restrict__ out,
                       const unsigned* __restrict__ slot, size_t n8) {
  const int bs = blockDim.x;
  size_t base = (size_t)blockIdx.x * bs * 4 + threadIdx.x;
  float qs = 127.0f / fmaxf(__uint_as_float(*slot), 1e-20f);
  bf16x8 v[4];
#pragma unroll
  for (int j = 0; j < 4; ++j)
    v[j] = *(const bf16x8*)(in + (base + (size_t)j * bs) * 8);
#pragma unroll
  for (int j = 0; j < 4; ++j) {
    unsigned lo = 0, hi = 0;
#pragma unroll
    for (int e = 0; e < 4; ++e) {
      int q = (int)rintf(fminf(fmaxf((float)v[j][e] * qs, -127.f), 127.f));
      lo |= (unsigned)(q & 255) << (8 * e);
    }
#pragma unroll
    for (int e = 0; e < 4; ++e) {
      int q = (int)rintf(fminf(fmaxf((float)v[j][4 + e] * qs, -127.f), 127.f));
      hi |= (unsigned)(q & 255) << (8 * e);
    }
    uint2 r{lo, hi};
    ((uint2*)out)[base + (size_t)j * bs] = r;
  }
}

extern "C" void kernel_launch(void* const* d_in, const int* in_sizes, int n_in,
                              void* d_out, int out_size, void* d_ws, size_t ws_size,
                              hipStream_t stream) {
  const float* x   = (const float*)d_in[0];  // [4, 4096, 256]
  const float* adj = (const float*)d_in[1];  // [4096, 4096]
  const float* S   = (const float*)d_in[2];  // [4096, 4096]
  const float* W1  = (const float*)d_in[3];  // [256, 512]
  const float* W2  = (const float*)d_in[4];  // [512, 1024]
  const float* W3  = (const float*)d_in[5];  // [1024, 256]

  const int N = 4096, F = 256, H1 = 512, H2 = 1024, NC = 256, B = 4;

  // Chain (adjacency GEMMs i8, support GEMMs bf16), R7 workspace (~98.5 MiB):
  char* ws = (char*)d_ws;
  int8_t* AWQ  = (int8_t*)ws; ws += (size_t)N * N;           // 16.8 MB
  bf16_t* SCR  = (bf16_t*)ws; ws += (size_t)B * N * H2 * 2;  // 33.5 MB partials/H2B
  int8_t* XQT  = (int8_t*)ws; ws += (size_t)B * F * N;       //  4.2 MB
  bf16_t* BufY = (bf16_t*)ws; ws += (size_t)B * N * H1 * 2;  // 16.8 MB G1/G2/ST3T
  bf16_t* BufZ = (bf16_t*)ws; ws += (size_t)B * N * H1 * 2;  // 16.8 MB H1T/st3 partials
  int8_t* QS   = (int8_t*)ws; ws += (size_t)B * H1 * N;      //  8.4 MB H1Q/ST3Q
  bf16_t* W1T  = (bf16_t*)ws; ws += (size_t)F * H1 * 2;
  bf16_t* W2T  = (bf16_t*)ws; ws += (size_t)H1 * H2 * 2;
  bf16_t* W3T  = (bf16_t*)ws; ws += (size_t)H2 * NC * 2;
  unsigned* SC = (unsigned*)ws;                              // 3 scale slots
  unsigned* SX = SC, *SH1 = SC + 1, *SST3 = SC + 2;

  bf16_t* G1 = BufY, *G2 = BufY, *ST3T = BufY;
  bf16_t* H1T = BufZ;
  bf16_t* H2B = SCR;
  int8_t* H1Q = QS, *ST3Q = QS;

  dim3 blk(THREADS);

  // prep: zero the 3 scale slots (graph-legal memset node), then one fused
  // kernel: absmax(x) | weight cast3 | AW_q quantize (nt loads).
  (void)hipMemsetAsync(SC, 0, 3 * sizeof(unsigned), stream);
  prep_kernel<<<PREP_AMX + PREP_C3 + PREP_MC, 256, 0, stream>>>(
      adj, S, AWQ, x, (size_t)B * N * F / 4, SX, W1, W2, W3, W1T, W2T, W3T);
  transpose_quant_x<<<dim3(N / 32, F / 32, B), 256, 0, stream>>>(x, XQT, SX);

  // L1: g1 = AWq @ xq, SK=2 -> SCR, reduce -> G1.  Grid (32,2,8) = 512 blocks.
  gemm_i8<<<dim3(N / BM, F / BN, B * 2), blk, 0, stream>>>(
      AWQ, XQT, SCR, N, F, N, N / 2, 0, (long)F * N, (long)N * F, SX);
  // groups = B*N*F/8 = 524,288 ; 1024*256*2 = 524,288 -> exact.
  reduce_k<2, false, false><<<1024, 256, 0, stream>>>(SCR, G1, (size_t)B * N * F, nullptr);
  //     h1^T = relu(g1 @ W1)^T -> H1T, absmax fused into epilogue -> SH1
  gemm_bt<1, true, true><<<dim3(N / BM, H1 / BN, B), blk, 0, stream>>>(
      G1, W1T, H1T, N, H1, F, F, (long)N * F, 0, (long)H1 * N, SH1);
  // n8 = 1,048,576 ; 1024*256*4 = 1,048,576 -> exact single shot.
  quant8<<<1024, 256, 0, stream>>>(H1T, H1Q, SH1, (size_t)B * H1 * N / 8);

  // L2: g2 = AWq @ h1q, NO split-K (direct write -> G2). Grid (32,4,4) = 512.
  gemm_i8<<<dim3(N / BM, H1 / BN, B), blk, 0, stream>>>(
      AWQ, H1Q, G2, N, H1, N, N, 0, (long)H1 * N, (long)N * H1, SH1);
  //     h2 = relu(g2 @ W2) -> H2B (SCR).  Grid (32,8,4) = 1024.
  gemm_bt<0, true, false><<<dim3(N / BM, H2 / BN, B), blk, 0, stream>>>(
      G2, W2T, H2B, N, H2, H1, H1, (long)N * H1, 0, (long)N * H2, nullptr);

  // L3: st3^T = (h2 @ W3)^T, SK=2 -> partials BufZ, reduce+absmax -> ST3T/SST3
  gemm_bt<1, false, false><<<dim3(N / BM, NC / BN, B * 2), blk, 0, stream>>>(
      H2B, W3T, BufZ, N, NC, H2, H2 / 2, (long)N * H2, 0, (long)NC * N, nullptr);
  // groups = 524,288 -> 1024 blocks exact.
  reduce_k<2, false, true><<<1024, 256, 0, stream>>>(BufZ, ST3T, (size_t)B * NC * N, SST3);
  // n8 = 524,288 ; 512*256*4 = 524,288 -> exact single shot.
  quant8<<<512, 256, 0, stream>>>(ST3T, ST3Q, SST3, (size_t)B * NC * N / 8);
  //     out = AWq @ st3q, SK=2 -> partials SCR, reduce f32 -> d_out
  gemm_i8<<<dim3(N / BM, NC / BN, B * 2), blk, 0, stream>>>(
      AWQ, ST3Q, SCR, N, NC, N, N / 2, 0, (long)NC * N, (long)N * NC, SST3);
  // groups = 524,288 -> 1024 blocks exact.
  reduce_k<2, true, false><<<1024, 256, 0, stream>>>(SCR, d_out, (size_t)B * N * NC, nullptr);
}

// Round 10
// 336.324 us; speedup vs baseline: 1.0322x; 1.0014x over previous
//
#include <hip/hip_runtime.h>
#include <hip/hip_bf16.h>
#include <stdint.h>
#include <stddef.h>

typedef __bf16 bf16x8 __attribute__((ext_vector_type(8)));
typedef float f32x4 __attribute__((ext_vector_type(4)));
typedef int i32x4 __attribute__((ext_vector_type(4)));
typedef __hip_bfloat16 bf16_t;

#define BM 128
#define BN 128
#define BK 64      // bf16 elements per K-tile (128 B rows)
#define BKQ 128    // i8 elements per K-tile (128 B rows -- same geometry)
#define THREADS 256

// async global->LDS, 16B per lane. LDS dest must be wave-uniform-base + lane*16.
__device__ __forceinline__ void stage16(const void* g, void* l) {
  __builtin_amdgcn_global_load_lds(
      (const __attribute__((address_space(1))) uint32_t*)g,
      (__attribute__((address_space(3))) uint32_t*)l, 16, 0, 0);
}

__device__ __forceinline__ unsigned pk2(float x, float y) {
  bf16_t a = __float2bfloat16(x);
  bf16_t b = __float2bfloat16(y);
  unsigned short ua = *(unsigned short*)&a;
  unsigned short ub = *(unsigned short*)&b;
  return (unsigned)ua | ((unsigned)ub << 16);
}

// R8: XCD chunk swizzle removed (R7 A/B: loss on gemms).
// R9: gemm_i8 double-buffered (+3us only -- barrier still drains vmcnt(0) for
//     the prefetch; counted-vmcnt needs >=3 buffers = 96KB = 1 block/CU on
//     this 4-wave tile. Parked; deeper pipeline = 256-tile rewrite, high risk).
// R10: gemm_bt gains dual-A accumulation (A2): h1 = P0@W1 + P1@W1 consumes
//     split-K partials directly -- kills the L1 reduce_k dispatch + ~50MB.

// ---------------- hierarchical absmax commit (1 atomic per BLOCK) ----------
// R7 lesson: WAVE-level atomics to one address serialize (~12ns each across
// XCDs); 8192 of them = 97us. Block-level (512-1024 staggered) is ~free.
__device__ __forceinline__ void block_max_commit(float m, unsigned* slot) {
  __shared__ float red[4];
#pragma unroll
  for (int off = 32; off > 0; off >>= 1)
    m = fmaxf(m, __shfl_xor(m, off, 64));
  if ((threadIdx.x & 63) == 0) red[threadIdx.x >> 6] = m;
  __syncthreads();
  if (threadIdx.x == 0) {
    float mm = fmaxf(fmaxf(red[0], red[1]), fmaxf(red[2], red[3]));
    atomicMax(slot, __float_as_uint(mm));
  }
}

// ---------------- bf16 GEMM (R3/R6-verified core; support GEMMs) -------------
// C = A @ Bt^T (+ A2 @ Bt^T if A2 != nullptr -- dual-A split-K-partial fusion).
// A:[M,K] row-major bf16 (row stride K, extent Kc). Bt:[N,K]. A2 has the SAME
// geometry/strides as A (b*sA + kz*Kc applied inside); the K-loop runs twice,
// accumulating into the same acc (GEMM is linear in A). B is re-staged in
// pass 2 (L2-hot, cheap).
// OUT_MODE 0: bf16 row-major [M,N]; 1: bf16 transposed [N,M]; 2: f32 row-major.
// blockIdx.z = kz*4 + b (B=4). Output chunk at z*sC.
// AMAX: fuse per-tensor absmax of outputs (block max -> 1 atomic).
// DO NOT MODIFY staging/LDS scheme (R4: 32-row fragments -> 1.7e7 conflicts).
template <int OUT_MODE, bool RELU, bool AMAX>
__global__ void gemm_bt(const bf16_t* __restrict__ A, const bf16_t* __restrict__ Bt,
                        void* __restrict__ Cv, int M, int N, int K, int Kc,
                        long sA, long sB, long sC, unsigned* __restrict__ amax,
                        const bf16_t* __restrict__ A2) {
  __shared__ __align__(16) char lds[(BM + BN) * BK * 2];  // 32 KB
  char* ldsA = lds;
  char* ldsB = lds + BM * BK * 2;

  const int t = threadIdx.x;
  const int lane = t & 63;
  const int w = t >> 6;
  const int wm = w >> 1, wn = w & 1;
  const int quad = lane >> 4, l15 = lane & 15;
  const int m0 = blockIdx.x * BM;
  const int n0 = blockIdx.y * BN;
  const int z = blockIdx.z;
  const int b = z & 3;
  const int kz = z >> 2;

  const bf16_t* Ab = A + (size_t)b * sA + (size_t)kz * Kc;
  const bf16_t* Bb = Bt + (size_t)b * sB + (size_t)kz * Kc;

  size_t aSrc[4], bSrc[4];
#pragma unroll
  for (int i = 0; i < 4; ++i) {
    int c = i * 256 + t;
    int r = c >> 3;
    int kcs = (c & 7) ^ (r & 7);
    aSrc[i] = (size_t)(m0 + r) * K + (size_t)kcs * 8;
    bSrc[i] = (size_t)(n0 + r) * K + (size_t)kcs * 8;
  }

  f32x4 acc[4][4];
#pragma unroll
  for (int mi = 0; mi < 4; ++mi)
#pragma unroll
    for (int ni = 0; ni < 4; ++ni)
      acc[mi][ni] = f32x4{0.f, 0.f, 0.f, 0.f};

  const int aRowB = (wm * 64 + l15) * (BK * 2);
  const int bRowB = (wn * 64 + l15) * (BK * 2);
  const int xc0 = (quad ^ (lane & 7)) * 16;

  for (int pass = 0; pass < 2; ++pass) {
    const bf16_t* Ap;
    if (pass == 0) {
      Ap = Ab;
    } else {
      if (!A2) break;  // wave-uniform
      Ap = A2 + (size_t)b * sA + (size_t)kz * Kc;
    }
    for (int k0 = 0; k0 < Kc; k0 += BK) {
#pragma unroll
      for (int i = 0; i < 4; ++i) {
        stage16(Ap + aSrc[i] + k0, ldsA + (i * 256 + t) * 16);
        stage16(Bb + bSrc[i] + k0, ldsB + (i * 256 + t) * 16);
      }
      __syncthreads();

#pragma unroll
      for (int ks = 0; ks < 2; ++ks) {
        const int xo = xc0 ^ (ks * 64);
        bf16x8 af[4], bfr[4];
#pragma unroll
        for (int mi = 0; mi < 4; ++mi)
          af[mi] = *(const bf16x8*)(ldsA + aRowB + mi * 2048 + xo);
#pragma unroll
        for (int ni = 0; ni < 4; ++ni)
          bfr[ni] = *(const bf16x8*)(ldsB + bRowB + ni * 2048 + xo);
#pragma unroll
        for (int mi = 0; mi < 4; ++mi)
#pragma unroll
          for (int ni = 0; ni < 4; ++ni)
            acc[mi][ni] = __builtin_amdgcn_mfma_f32_16x16x32_bf16(
                af[mi], bfr[ni], acc[mi][ni], 0, 0, 0);
      }
      __syncthreads();
    }
  }

  const int mBase = m0 + wm * 64 + quad * 4;
  const int nBase = n0 + wn * 64 + l15;
  float mval = 0.f;

  if (OUT_MODE == 1) {
    bf16_t* Ct = (bf16_t*)Cv + (size_t)z * sC;
#pragma unroll
    for (int ni = 0; ni < 4; ++ni) {
      size_t colOff = (size_t)(nBase + ni * 16) * (size_t)M;
#pragma unroll
      for (int mi = 0; mi < 4; ++mi) {
        int rr = mBase + mi * 16;
        float v0 = acc[mi][ni][0], v1 = acc[mi][ni][1];
        float v2 = acc[mi][ni][2], v3 = acc[mi][ni][3];
        if (RELU) {
          v0 = fmaxf(v0, 0.f); v1 = fmaxf(v1, 0.f);
          v2 = fmaxf(v2, 0.f); v3 = fmaxf(v3, 0.f);
        }
        if (AMAX) {
          mval = fmaxf(mval, fmaxf(fmaxf(fabsf(v0), fabsf(v1)),
                                   fmaxf(fabsf(v2), fabsf(v3))));
        }
        uint2 pkv;
        pkv.x = pk2(v0, v1);
        pkv.y = pk2(v2, v3);
        *(uint2*)(Ct + colOff + rr) = pkv;
      }
    }
  } else if (OUT_MODE == 0) {
    bf16_t* C = (bf16_t*)Cv + (size_t)z * sC;
#pragma unroll
    for (int mi = 0; mi < 4; ++mi) {
#pragma unroll
      for (int j = 0; j < 4; ++j) {
        size_t rowOff = (size_t)(mBase + mi * 16 + j) * (size_t)N;
#pragma unroll
        for (int ni = 0; ni < 4; ++ni) {
          float v = acc[mi][ni][j];
          if (RELU) v = fmaxf(v, 0.f);
          if (AMAX) mval = fmaxf(mval, fabsf(v));
          C[rowOff + nBase + ni * 16] = __float2bfloat16(v);
        }
      }
    }
  } else {
    float* C = (float*)Cv + (size_t)z * sC;
#pragma unroll
    for (int mi = 0; mi < 4; ++mi) {
#pragma unroll
      for (int j = 0; j < 4; ++j) {
        size_t rowOff = (size_t)(mBase + mi * 16 + j) * (size_t)N;
#pragma unroll
        for (int ni = 0; ni < 4; ++ni) {
          float v = acc[mi][ni][j];
          if (RELU) v = fmaxf(v, 0.f);
          C[rowOff + nBase + ni * 16] = v;
        }
      }
    }
  }

  if (AMAX) block_max_commit(mval, amax);
}

// ---------------- int8 GEMM (adjacency GEMMs; R7-validated core) -------------
// BKQ=128 i8 = 128 B rows. A: AW_q (static scale 127). B: per-tensor scale mx
// in *slot. Epilogue: v = acc * mx / 127^2. Output bf16 row-major at z*sC.
// R9: explicit LDS double-buffer (2-phase). Gain was small (+1us/dispatch):
// the end-of-iter barrier still drains vmcnt(0) for the prefetch (2-buffer
// scheme requires it). Kept: it's not worse and saves one barrier per K-step.
__global__ void gemm_i8(const int8_t* __restrict__ A, const int8_t* __restrict__ Bt,
                        bf16_t* __restrict__ C, int M, int N, int K, int Kc,
                        long sA, long sB, long sC,
                        const unsigned* __restrict__ slot) {
  __shared__ __align__(16) char lds[2 * (BM + BN) * BKQ];  // 64 KB (2 buffers)
  const int BUF = (BM + BN) * BKQ;                          // 32768

  const int t = threadIdx.x;
  const int lane = t & 63;
  const int w = t >> 6;
  const int wm = w >> 1, wn = w & 1;
  const int quad = lane >> 4, l15 = lane & 15;
  const int m0 = blockIdx.x * BM;
  const int n0 = blockIdx.y * BN;
  const int z = blockIdx.z;
  const int b = z & 3;
  const int kz = z >> 2;

  const int8_t* Ab = A + (size_t)b * sA + (size_t)kz * Kc;
  const int8_t* Bb = Bt + (size_t)b * sB + (size_t)kz * Kc;

  size_t aSrc[4], bSrc[4];
#pragma unroll
  for (int i = 0; i < 4; ++i) {
    int c = i * 256 + t;
    int r = c >> 3;
    int kcs = (c & 7) ^ (r & 7);
    aSrc[i] = (size_t)(m0 + r) * K + (size_t)kcs * 16;  // 16 i8 per chunk
    bSrc[i] = (size_t)(n0 + r) * K + (size_t)kcs * 16;
  }

  i32x4 acc[4][4];
#pragma unroll
  for (int mi = 0; mi < 4; ++mi)
#pragma unroll
    for (int ni = 0; ni < 4; ++ni)
      acc[mi][ni] = i32x4{0, 0, 0, 0};

  const int aRowB = (wm * 64 + l15) * BKQ;
  const int bRowB = (wn * 64 + l15) * BKQ;
  const int xc0 = (quad ^ (lane & 7)) * 16;

  // prologue: stage K-tile 0 into buffer 0
#pragma unroll
  for (int i = 0; i < 4; ++i) {
    stage16(Ab + aSrc[i], lds + (i * 256 + t) * 16);
    stage16(Bb + bSrc[i], lds + BM * BKQ + (i * 256 + t) * 16);
  }
  __syncthreads();

  int cur = 0;
  for (int k0 = 0; k0 < Kc; k0 += BKQ) {
    const int nxt = k0 + BKQ;
    if (nxt < Kc) {  // wave-uniform branch
      char* dst = lds + (cur ^ 1) * BUF;
#pragma unroll
      for (int i = 0; i < 4; ++i) {
        stage16(Ab + aSrc[i] + nxt, dst + (i * 256 + t) * 16);
        stage16(Bb + bSrc[i] + nxt, dst + BM * BKQ + (i * 256 + t) * 16);
      }
    }
    const char* ldsA = lds + cur * BUF;
    const char* ldsB = ldsA + BM * BKQ;

#pragma unroll
    for (int ks = 0; ks < 2; ++ks) {        // two K=64 MFMA steps per BKQ=128
      const int xo = xc0 ^ (ks * 64);
      i32x4 af[4], bfr[4];
#pragma unroll
      for (int mi = 0; mi < 4; ++mi)
        af[mi] = *(const i32x4*)(ldsA + aRowB + mi * 2048 + xo);
#pragma unroll
      for (int ni = 0; ni < 4; ++ni)
        bfr[ni] = *(const i32x4*)(ldsB + bRowB + ni * 2048 + xo);
#pragma unroll
      for (int mi = 0; mi < 4; ++mi)
#pragma unroll
        for (int ni = 0; ni < 4; ++ni)
          acc[mi][ni] = __builtin_amdgcn_mfma_i32_16x16x64_i8(
              af[mi], bfr[ni], acc[mi][ni], 0, 0, 0);
    }
    __syncthreads();   // one barrier per K-step: drains t+1 loads, guards reuse
    cur ^= 1;
  }

  const float mx = fmaxf(__uint_as_float(*slot), 1e-20f);
  const float sc = mx * (1.0f / 16129.0f);  // / (127*127)

  const int mBase = m0 + wm * 64 + quad * 4;
  const int nBase = n0 + wn * 64 + l15;
  bf16_t* Cb = C + (size_t)z * sC;
#pragma unroll
  for (int mi = 0; mi < 4; ++mi) {
#pragma unroll
    for (int j = 0; j < 4; ++j) {
      size_t rowOff = (size_t)(mBase + mi * 16 + j) * (size_t)N;
#pragma unroll
      for (int ni = 0; ni < 4; ++ni)
        Cb[rowOff + nBase + ni * 16] = __float2bfloat16((float)acc[mi][ni][j] * sc);
    }
  }
}

// Sum SK bf16 partial chunks (stride tot) in fp32; write bf16 or f32.
// AMAX: fuse per-tensor absmax of the summed outputs (block max -> 1 atomic).
// CONTRACT: (tot/8) % (gridDim.x * blockDim.x * 2) == 0 at every call site.
template <int SK, bool F32OUT, bool AMAX>
__global__ void reduce_k(const bf16_t* __restrict__ pp, void* __restrict__ out,
                         size_t tot, unsigned* __restrict__ amax) {
  const int bs = blockDim.x;
  size_t base = (size_t)blockIdx.x * bs * 2 + threadIdx.x;  // 8-elem group idx
  bf16x8 v[2][SK];
#pragma unroll
  for (int u = 0; u < 2; ++u) {
    size_t g = base + (size_t)u * bs;
#pragma unroll
    for (int kz = 0; kz < SK; ++kz)
      v[u][kz] = *(const bf16x8*)(pp + (size_t)kz * tot + g * 8);
  }
  float mval = 0.f;
#pragma unroll
  for (int u = 0; u < 2; ++u) {
    size_t g = base + (size_t)u * bs;
    float s[8];
#pragma unroll
    for (int j = 0; j < 8; ++j) s[j] = 0.f;
#pragma unroll
    for (int kz = 0; kz < SK; ++kz)
#pragma unroll
      for (int j = 0; j < 8; ++j) s[j] += (float)v[u][kz][j];
    if (AMAX) {
#pragma unroll
      for (int j = 0; j < 8; ++j) mval = fmaxf(mval, fabsf(s[j]));
    }
    if (F32OUT) {
      float* o = (float*)out + g * 8;
      float4 r0{s[0], s[1], s[2], s[3]};
      float4 r1{s[4], s[5], s[6], s[7]};
      ((float4*)o)[0] = r0;
      ((float4*)o)[1] = r1;
    } else {
      uint4 r;
      r.x = pk2(s[0], s[1]);
      r.y = pk2(s[2], s[3]);
      r.z = pk2(s[4], s[5]);
      r.w = pk2(s[6], s[7]);
      *(uint4*)((bf16_t*)out + g * 8) = r;
    }
  }
  if (AMAX) block_max_commit(mval, amax);
}

// ---------------- fused prep kernel (one launch, partitioned grid) ----------
// Segment A (blocks [0,512)):          absmax(x) -> SX  (grid-stride, 2 iters)
// Segment B (blocks [512,512+3584)):   W1/W2/W3 transpose+cast. 3584*256 =
//                                      917504 = n1+n2+n3 EXACTLY (R2 bug: 5120
//                                      here overran W3T by ~1MB, clobbering SC).
// Segment C (blocks [4096,4096+16384)): AW_q = round(adj*S*127), 1 float4/thr.
//   R7 CONFIRMED: nontemporal loads on adj/S dropped prep out of the top-5
//   (was 59us) -- the 134MB read-once stream was polluting the cache
//   hierarchy. KEEP nt. AWQ store stays cached (re-read 3x by gemms).
// SX/SH1/SST3 slots are zeroed by a hipMemsetAsync node BEFORE this kernel.
#define PREP_AMX 512
#define PREP_C3  3584   // (256*512 + 512*1024 + 1024*256) / 256  == 3584
#define PREP_MC  16384  // (4096*4096/4) / 256

__global__ void prep_kernel(const float* __restrict__ adj, const float* __restrict__ S,
                            int8_t* __restrict__ o,
                            const float* __restrict__ x, size_t n4x,
                            unsigned* __restrict__ SX,
                            const float* __restrict__ W1, const float* __restrict__ W2,
                            const float* __restrict__ W3, bf16_t* __restrict__ W1T,
                            bf16_t* __restrict__ W2T, bf16_t* __restrict__ W3T) {
  const int bid = blockIdx.x;
  const int tid = threadIdx.x;

  if (bid < PREP_AMX) {
    // absmax over x (f32), 4 float4 loads in flight per iter
    size_t base = (size_t)bid * (256 * 4) + tid;
    const size_t stride = (size_t)PREP_AMX * 256 * 4;
    float m = 0.f;
    for (; base + 3 * 256 < n4x; base += stride) {
      float4 v[4];
#pragma unroll
      for (int j = 0; j < 4; ++j) v[j] = ((const float4*)x)[base + (size_t)j * 256];
#pragma unroll
      for (int j = 0; j < 4; ++j)
        m = fmaxf(m, fmaxf(fmaxf(fabsf(v[j].x), fabsf(v[j].y)),
                           fmaxf(fabsf(v[j].z), fabsf(v[j].w))));
    }
    block_max_commit(m, SX);
  } else if (bid < PREP_AMX + PREP_C3) {
    const int n1 = 256 * 512;
    const int n2 = 512 * 1024;
    const int n3 = 1024 * 256;
    int idx = (bid - PREP_AMX) * 256 + tid;
    if (idx < n1) {
      int K = 256, H = 512;
      int h = idx / K, k = idx - h * K;
      W1T[idx] = __float2bfloat16(W1[(size_t)k * H + h]);
    } else if (idx < n1 + n2) {
      int i = idx - n1;
      int K = 512, H = 1024;
      int h = i / K, k = i - h * K;
      W2T[i] = __float2bfloat16(W2[(size_t)k * H + h]);
    } else if (idx < n1 + n2 + n3) {
      int i = idx - n1 - n2;
      int K = 1024, H = 256;
      int h = i / K, k = i - h * K;
      W3T[i] = __float2bfloat16(W3[(size_t)k * H + h]);
    }
  } else {
    int i = (bid - PREP_AMX - PREP_C3) * 256 + tid;
    f32x4 av = __builtin_nontemporal_load((const f32x4*)adj + i);
    f32x4 sv = __builtin_nontemporal_load((const f32x4*)S + i);
    float v0 = av[0] * sv[0] * 127.f, v1 = av[1] * sv[1] * 127.f;
    float v2 = av[2] * sv[2] * 127.f, v3 = av[3] * sv[3] * 127.f;
    int q0 = (int)rintf(fminf(fmaxf(v0, -127.f), 127.f));
    int q1 = (int)rintf(fminf(fmaxf(v1, -127.f), 127.f));
    int q2 = (int)rintf(fminf(fmaxf(v2, -127.f), 127.f));
    int q3 = (int)rintf(fminf(fmaxf(v3, -127.f), 127.f));
    unsigned p = (unsigned)(q0 & 255) | ((unsigned)(q1 & 255) << 8) |
                 ((unsigned)(q2 & 255) << 16) | ((unsigned)(q3 & 255) << 24);
    ((unsigned*)o)[i] = p;
  }
}

// x [B][4096][256] f32 -> xt [B][256][4096] i8 (scale 127/mx from slot)
__global__ void transpose_quant_x(const float* __restrict__ x, int8_t* __restrict__ xt,
                                  const unsigned* __restrict__ slot) {
  __shared__ float tile[32][33];
  const int N = 4096, F = 256;
  float qs = 127.0f / fmaxf(__uint_as_float(*slot), 1e-20f);
  int n0 = blockIdx.x * 32, f0 = blockIdx.y * 32, b = blockIdx.z;
  const float* xb = x + (size_t)b * N * F;
  int8_t* xtb = xt + (size_t)b * N * F;
  int tx = threadIdx.x & 31, ty = threadIdx.x >> 5;  // 32 x 8
#pragma unroll
  for (int i = 0; i < 32; i += 8)
    tile[ty + i][tx] = xb[(size_t)(n0 + ty + i) * F + f0 + tx];
  __syncthreads();
#pragma unroll
  for (int i = 0; i < 32; i += 8) {
    float v = tile[tx][ty + i] * qs;
    xtb[(size_t)(f0 + ty + i) * N + n0 + tx] =
        (int8_t)(int)rintf(fminf(fmaxf(v, -127.f), 127.f));
  }
}

// bf16 -> i8 with scale 127/mx from slot; 4 groups of 8 elems per thread.
// CONTRACT: n8 % (gridDim.x * blockDim.x * 4) == 0 at every call site.
__global__ void quant8(const bf16_t* __restrict__ in, int8_t* __restrict__ out,
                       const unsigned* __restrict__ slot, size_t n8) {
  const int bs = blockDim.x;
  size_t base = (size_t)blockIdx.x * bs * 4 + threadIdx.x;
  float qs = 127.0f / fmaxf(__uint_as_float(*slot), 1e-20f);
  bf16x8 v[4];
#pragma unroll
  for (int j = 0; j < 4; ++j)
    v[j] = *(const bf16x8*)(in + (base + (size_t)j * bs) * 8);
#pragma unroll
  for (int j = 0; j < 4; ++j) {
    unsigned lo = 0, hi = 0;
#pragma unroll
    for (int e = 0; e < 4; ++e) {
      int q = (int)rintf(fminf(fmaxf((float)v[j][e] * qs, -127.f), 127.f));
      lo |= (unsigned)(q & 255) << (8 * e);
    }
#pragma unroll
    for (int e = 0; e < 4; ++e) {
      int q = (int)rintf(fminf(fmaxf((float)v[j][4 + e] * qs, -127.f), 127.f));
      hi |= (unsigned)(q & 255) << (8 * e);
    }
    uint2 r{lo, hi};
    ((uint2*)out)[base + (size_t)j * bs] = r;
  }
}

extern "C" void kernel_launch(void* const* d_in, const int* in_sizes, int n_in,
                              void* d_out, int out_size, void* d_ws, size_t ws_size,
                              hipStream_t stream) {
  const float* x   = (const float*)d_in[0];  // [4, 4096, 256]
  const float* adj = (const float*)d_in[1];  // [4096, 4096]
  const float* S   = (const float*)d_in[2];  // [4096, 4096]
  const float* W1  = (const float*)d_in[3];  // [256, 512]
  const float* W2  = (const float*)d_in[4];  // [512, 1024]
  const float* W3  = (const float*)d_in[5];  // [1024, 256]

  const int N = 4096, F = 256, H1 = 512, H2 = 1024, NC = 256, B = 4;

  // Chain (adjacency GEMMs i8, support GEMMs bf16), R7 workspace (~98.5 MiB):
  char* ws = (char*)d_ws;
  int8_t* AWQ  = (int8_t*)ws; ws += (size_t)N * N;           // 16.8 MB
  bf16_t* SCR  = (bf16_t*)ws; ws += (size_t)B * N * H2 * 2;  // 33.5 MB partials/H2B
  int8_t* XQT  = (int8_t*)ws; ws += (size_t)B * F * N;       //  4.2 MB
  bf16_t* BufY = (bf16_t*)ws; ws += (size_t)B * N * H1 * 2;  // 16.8 MB G2/ST3T
  bf16_t* BufZ = (bf16_t*)ws; ws += (size_t)B * N * H1 * 2;  // 16.8 MB H1T/st3 partials
  int8_t* QS   = (int8_t*)ws; ws += (size_t)B * H1 * N;      //  8.4 MB H1Q/ST3Q
  bf16_t* W1T  = (bf16_t*)ws; ws += (size_t)F * H1 * 2;
  bf16_t* W2T  = (bf16_t*)ws; ws += (size_t)H1 * H2 * 2;
  bf16_t* W3T  = (bf16_t*)ws; ws += (size_t)H2 * NC * 2;
  unsigned* SC = (unsigned*)ws;                              // 3 scale slots
  unsigned* SX = SC, *SH1 = SC + 1, *SST3 = SC + 2;

  bf16_t* G2 = BufY, *ST3T = BufY;
  bf16_t* H1T = BufZ;
  bf16_t* H2B = SCR;
  int8_t* H1Q = QS, *ST3Q = QS;

  dim3 blk(THREADS);

  // prep: zero the 3 scale slots (graph-legal memset node), then one fused
  // kernel: absmax(x) | weight cast3 | AW_q quantize (nt loads).
  (void)hipMemsetAsync(SC, 0, 3 * sizeof(unsigned), stream);
  prep_kernel<<<PREP_AMX + PREP_C3 + PREP_MC, 256, 0, stream>>>(
      adj, S, AWQ, x, (size_t)B * N * F / 4, SX, W1, W2, W3, W1T, W2T, W3T);
  transpose_quant_x<<<dim3(N / 32, F / 32, B), 256, 0, stream>>>(x, XQT, SX);

  // L1: g1 = AWq @ xq, SK=2 -> SCR partials P0 (z=0..3) and P1 (z=4..7).
  //     Grid (32,2,8) = 512 blocks.
  gemm_i8<<<dim3(N / BM, F / BN, B * 2), blk, 0, stream>>>(
      AWQ, XQT, SCR, N, F, N, N / 2, 0, (long)F * N, (long)N * F, SX);
  //     h1^T = relu((P0+P1) @ W1)^T via DUAL-A (R10: reduce_k L1 eliminated;
  //     GEMM linear in A). A = P0 chunks (b*sA), A2 = P1 chunks (+4*N*F).
  //     absmax fused into epilogue -> SH1.
  gemm_bt<1, true, true><<<dim3(N / BM, H1 / BN, B), blk, 0, stream>>>(
      SCR, W1T, H1T, N, H1, F, F, (long)N * F, 0, (long)H1 * N, SH1,
      SCR + (size_t)4 * N * F);
  // n8 = 1,048,576 ; 1024*256*4 = 1,048,576 -> exact single shot.
  quant8<<<1024, 256, 0, stream>>>(H1T, H1Q, SH1, (size_t)B * H1 * N / 8);

  // L2: g2 = AWq @ h1q, NO split-K (direct write -> G2). Grid (32,4,4) = 512.
  gemm_i8<<<dim3(N / BM, H1 / BN, B), blk, 0, stream>>>(
      AWQ, H1Q, G2, N, H1, N, N, 0, (long)H1 * N, (long)N * H1, SH1);
  //     h2 = relu(g2 @ W2) -> H2B (SCR).  Grid (32,8,4) = 1024.
  gemm_bt<0, true, false><<<dim3(N / BM, H2 / BN, B), blk, 0, stream>>>(
      G2, W2T, H2B, N, H2, H1, H1, (long)N * H1, 0, (long)N * H2, nullptr,
      nullptr);

  // L3: st3^T = (h2 @ W3)^T, SK=2 -> partials BufZ, reduce+absmax -> ST3T/SST3
  //     (reduce NOT fusable here: quant8 needs the materialized sum + final max)
  gemm_bt<1, false, false><<<dim3(N / BM, NC / BN, B * 2), blk, 0, stream>>>(
      H2B, W3T, BufZ, N, NC, H2, H2 / 2, (long)N * H2, 0, (long)NC * N, nullptr,
      nullptr);
  // groups = 524,288 -> 1024 blocks exact.
  reduce_k<2, false, true><<<1024, 256, 0, stream>>>(BufZ, ST3T, (size_t)B * NC * N, SST3);
  // n8 = 524,288 ; 512*256*4 = 524,288 -> exact single shot.
  quant8<<<512, 256, 0, stream>>>(ST3T, ST3Q, SST3, (size_t)B * NC * N / 8);
  //     out = AWq @ st3q, SK=2 -> partials SCR, reduce f32 -> d_out
  gemm_i8<<<dim3(N / BM, NC / BN, B * 2), blk, 0, stream>>>(
      AWQ, ST3Q, SCR, N, NC, N, N / 2, 0, (long)NC * N, (long)N * NC, SST3);
  // groups = 524,288 -> 1024 blocks exact.
  reduce_k<2, true, false><<<1024, 256, 0, stream>>>(SCR, d_out, (size_t)B * N * NC, nullptr);
}

// Round 11
// 331.134 us; speedup vs baseline: 1.0484x; 1.0157x over previous
//
#include <hip/hip_runtime.h>
#include <hip/hip_bf16.h>
#include <stdint.h>
#include <stddef.h>

typedef __bf16 bf16x8 __attribute__((ext_vector_type(8)));
typedef float f32x4 __attribute__((ext_vector_type(4)));
typedef int i32x4 __attribute__((ext_vector_type(4)));
typedef __hip_bfloat16 bf16_t;

#define BM 128
#define BN 128
#define BK 64      // bf16 elements per K-tile (128 B rows)
#define BKQ 128    // i8 elements per K-tile (128 B rows -- same geometry)
#define GT 512     // R11: gemm blocks are 8 waves (was 4) -- 2x waves/SIMD

// async global->LDS, 16B per lane. LDS dest must be wave-uniform-base + lane*16.
__device__ __forceinline__ void stage16(const void* g, void* l) {
  __builtin_amdgcn_global_load_lds(
      (const __attribute__((address_space(1))) uint32_t*)g,
      (__attribute__((address_space(3))) uint32_t*)l, 16, 0, 0);
}

__device__ __forceinline__ unsigned pk2(float x, float y) {
  bf16_t a = __float2bfloat16(x);
  bf16_t b = __float2bfloat16(y);
  unsigned short ua = *(unsigned short*)&a;
  unsigned short ub = *(unsigned short*)&b;
  return (unsigned)ua | ((unsigned)ub << 16);
}

// R8:  XCD chunk swizzle removed (R7 A/B: loss on gemms).
// R9:  gemm_i8 double-buffered (small gain; 2-buffer scheme still drains
//      vmcnt(0) at the barrier).
// R10: gemm_bt dual-A (split-K-partial fusion). Net ~0 but numerically cleaner.
// R11: BOTH gemm kernels go 512-thread / 8-wave (2x4 wave grid, 64x32 output
//      per wave, acc[4][2]). LDS byte image and per-wave read patterns are
//      UNCHANGED (staging index c=i*512+t enumerates the same chunks; R8
//      showed 0 bank conflicts). Purpose: waves/CU 8->16 (i8) to hide the
//      per-K-step load-drain latency (R8: MfmaUtil 30%, occ 17.5%).

// ---------------- hierarchical absmax commit (1 atomic per BLOCK) ----------
// R7 lesson: WAVE-level atomics to one address serialize; block-level is free.
// Works for 4-wave (256t) and 8-wave (512t) blocks (dynamic wave count).
__device__ __forceinline__ void block_max_commit(float m, unsigned* slot) {
  __shared__ float red[8];
#pragma unroll
  for (int off = 32; off > 0; off >>= 1)
    m = fmaxf(m, __shfl_xor(m, off, 64));
  if ((threadIdx.x & 63) == 0) red[threadIdx.x >> 6] = m;
  __syncthreads();
  if (threadIdx.x == 0) {
    const int nw = blockDim.x >> 6;
    float mm = red[0];
    for (int i = 1; i < nw; ++i) mm = fmaxf(mm, red[i]);
    atomicMax(slot, __float_as_uint(mm));
  }
}

// ---------------- bf16 GEMM (512-thread / 8-wave since R11) ------------------
// C = A @ Bt^T (+ A2 @ Bt^T if A2 != nullptr -- dual-A split-K-partial fusion).
// A:[M,K] row-major bf16 (row stride K, extent Kc). Bt:[N,K].
// OUT_MODE 0: bf16 row-major [M,N]; 1: bf16 transposed [N,M]; 2: f32 row-major.
// blockIdx.z = kz*4 + b (B=4). Output chunk at z*sC.
// Wave map: 8 waves as 2(M) x 4(N); each wave owns 64x32 of C; acc[4][2].
// DO NOT MODIFY staging/LDS byte layout (R4: 32-row fragments -> conflicts).
template <int OUT_MODE, bool RELU, bool AMAX>
__global__ __launch_bounds__(GT) void gemm_bt(
    const bf16_t* __restrict__ A, const bf16_t* __restrict__ Bt,
    void* __restrict__ Cv, int M, int N, int K, int Kc,
    long sA, long sB, long sC, unsigned* __restrict__ amax,
    const bf16_t* __restrict__ A2) {
  __shared__ __align__(16) char lds[(BM + BN) * BK * 2];  // 32 KB
  char* ldsA = lds;
  char* ldsB = lds + BM * BK * 2;

  const int t = threadIdx.x;
  const int lane = t & 63;
  const int w = t >> 6;             // 0..7
  const int wm = w >> 2, wn = w & 3;
  const int quad = lane >> 4, l15 = lane & 15;
  const int m0 = blockIdx.x * BM;
  const int n0 = blockIdx.y * BN;
  const int z = blockIdx.z;
  const int b = z & 3;
  const int kz = z >> 2;

  const bf16_t* Ab = A + (size_t)b * sA + (size_t)kz * Kc;
  const bf16_t* Bb = Bt + (size_t)b * sB + (size_t)kz * Kc;

  size_t aSrc[2], bSrc[2];
#pragma unroll
  for (int i = 0; i < 2; ++i) {
    int c = i * GT + t;             // same chunk enumeration as 4x256 (R4 image)
    int r = c >> 3;
    int kcs = (c & 7) ^ (r & 7);
    aSrc[i] = (size_t)(m0 + r) * K + (size_t)kcs * 8;
    bSrc[i] = (size_t)(n0 + r) * K + (size_t)kcs * 8;
  }

  f32x4 acc[4][2];
#pragma unroll
  for (int mi = 0; mi < 4; ++mi)
#pragma unroll
    for (int ni = 0; ni < 2; ++ni)
      acc[mi][ni] = f32x4{0.f, 0.f, 0.f, 0.f};

  const int aRowB = (wm * 64 + l15) * (BK * 2);
  const int bRowB = (wn * 32 + l15) * (BK * 2);
  const int xc0 = (quad ^ (lane & 7)) * 16;

  for (int pass = 0; pass < 2; ++pass) {
    const bf16_t* Ap;
    if (pass == 0) {
      Ap = Ab;
    } else {
      if (!A2) break;  // wave-uniform
      Ap = A2 + (size_t)b * sA + (size_t)kz * Kc;
    }
    for (int k0 = 0; k0 < Kc; k0 += BK) {
#pragma unroll
      for (int i = 0; i < 2; ++i) {
        stage16(Ap + aSrc[i] + k0, ldsA + (i * GT + t) * 16);
        stage16(Bb + bSrc[i] + k0, ldsB + (i * GT + t) * 16);
      }
      __syncthreads();

#pragma unroll
      for (int ks = 0; ks < 2; ++ks) {
        const int xo = xc0 ^ (ks * 64);
        bf16x8 af[4], bfr[2];
#pragma unroll
        for (int mi = 0; mi < 4; ++mi)
          af[mi] = *(const bf16x8*)(ldsA + aRowB + mi * 2048 + xo);
#pragma unroll
        for (int ni = 0; ni < 2; ++ni)
          bfr[ni] = *(const bf16x8*)(ldsB + bRowB + ni * 2048 + xo);
#pragma unroll
        for (int mi = 0; mi < 4; ++mi)
#pragma unroll
          for (int ni = 0; ni < 2; ++ni)
            acc[mi][ni] = __builtin_amdgcn_mfma_f32_16x16x32_bf16(
                af[mi], bfr[ni], acc[mi][ni], 0, 0, 0);
      }
      __syncthreads();
    }
  }

  const int mBase = m0 + wm * 64 + quad * 4;
  const int nBase = n0 + wn * 32 + l15;
  float mval = 0.f;

  if (OUT_MODE == 1) {
    bf16_t* Ct = (bf16_t*)Cv + (size_t)z * sC;
#pragma unroll
    for (int ni = 0; ni < 2; ++ni) {
      size_t colOff = (size_t)(nBase + ni * 16) * (size_t)M;
#pragma unroll
      for (int mi = 0; mi < 4; ++mi) {
        int rr = mBase + mi * 16;
        float v0 = acc[mi][ni][0], v1 = acc[mi][ni][1];
        float v2 = acc[mi][ni][2], v3 = acc[mi][ni][3];
        if (RELU) {
          v0 = fmaxf(v0, 0.f); v1 = fmaxf(v1, 0.f);
          v2 = fmaxf(v2, 0.f); v3 = fmaxf(v3, 0.f);
        }
        if (AMAX) {
          mval = fmaxf(mval, fmaxf(fmaxf(fabsf(v0), fabsf(v1)),
                                   fmaxf(fabsf(v2), fabsf(v3))));
        }
        uint2 pkv;
        pkv.x = pk2(v0, v1);
        pkv.y = pk2(v2, v3);
        *(uint2*)(Ct + colOff + rr) = pkv;
      }
    }
  } else if (OUT_MODE == 0) {
    bf16_t* C = (bf16_t*)Cv + (size_t)z * sC;
#pragma unroll
    for (int mi = 0; mi < 4; ++mi) {
#pragma unroll
      for (int j = 0; j < 4; ++j) {
        size_t rowOff = (size_t)(mBase + mi * 16 + j) * (size_t)N;
#pragma unroll
        for (int ni = 0; ni < 2; ++ni) {
          float v = acc[mi][ni][j];
          if (RELU) v = fmaxf(v, 0.f);
          if (AMAX) mval = fmaxf(mval, fabsf(v));
          C[rowOff + nBase + ni * 16] = __float2bfloat16(v);
        }
      }
    }
  } else {
    float* C = (float*)Cv + (size_t)z * sC;
#pragma unroll
    for (int mi = 0; mi < 4; ++mi) {
#pragma unroll
      for (int j = 0; j < 4; ++j) {
        size_t rowOff = (size_t)(mBase + mi * 16 + j) * (size_t)N;
#pragma unroll
        for (int ni = 0; ni < 2; ++ni) {
          float v = acc[mi][ni][j];
          if (RELU) v = fmaxf(v, 0.f);
          C[rowOff + nBase + ni * 16] = v;
        }
      }
    }
  }

  if (AMAX) block_max_commit(mval, amax);
}

// ---------------- int8 GEMM (512-thread / 8-wave since R11) ------------------
// BKQ=128 i8 = 128 B rows. A: AW_q (static scale 127). B: per-tensor scale mx
// in *slot. Epilogue: v = acc * mx / 127^2. Output bf16 row-major at z*sC.
// R9 double-buffer kept; R11 adds 8 waves (2x4), 64x32 C per wave, acc[4][2].
__global__ __launch_bounds__(GT) void gemm_i8(
    const int8_t* __restrict__ A, const int8_t* __restrict__ Bt,
    bf16_t* __restrict__ C, int M, int N, int K, int Kc,
    long sA, long sB, long sC, const unsigned* __restrict__ slot) {
  __shared__ __align__(16) char lds[2 * (BM + BN) * BKQ];  // 64 KB (2 buffers)
  const int BUF = (BM + BN) * BKQ;                          // 32768

  const int t = threadIdx.x;
  const int lane = t & 63;
  const int w = t >> 6;             // 0..7
  const int wm = w >> 2, wn = w & 3;
  const int quad = lane >> 4, l15 = lane & 15;
  const int m0 = blockIdx.x * BM;
  const int n0 = blockIdx.y * BN;
  const int z = blockIdx.z;
  const int b = z & 3;
  const int kz = z >> 2;

  const int8_t* Ab = A + (size_t)b * sA + (size_t)kz * Kc;
  const int8_t* Bb = Bt + (size_t)b * sB + (size_t)kz * Kc;

  size_t aSrc[2], bSrc[2];
#pragma unroll
  for (int i = 0; i < 2; ++i) {
    int c = i * GT + t;
    int r = c >> 3;
    int kcs = (c & 7) ^ (r & 7);
    aSrc[i] = (size_t)(m0 + r) * K + (size_t)kcs * 16;  // 16 i8 per chunk
    bSrc[i] = (size_t)(n0 + r) * K + (size_t)kcs * 16;
  }

  i32x4 acc[4][2];
#pragma unroll
  for (int mi = 0; mi < 4; ++mi)
#pragma unroll
    for (int ni = 0; ni < 2; ++ni)
      acc[mi][ni] = i32x4{0, 0, 0, 0};

  const int aRowB = (wm * 64 + l15) * BKQ;
  const int bRowB = (wn * 32 + l15) * BKQ;
  const int xc0 = (quad ^ (lane & 7)) * 16;

  // prologue: stage K-tile 0 into buffer 0
#pragma unroll
  for (int i = 0; i < 2; ++i) {
    stage16(Ab + aSrc[i], lds + (i * GT + t) * 16);
    stage16(Bb + bSrc[i], lds + BM * BKQ + (i * GT + t) * 16);
  }
  __syncthreads();

  int cur = 0;
  for (int k0 = 0; k0 < Kc; k0 += BKQ) {
    const int nxt = k0 + BKQ;
    if (nxt < Kc) {  // wave-uniform branch
      char* dst = lds + (cur ^ 1) * BUF;
#pragma unroll
      for (int i = 0; i < 2; ++i) {
        stage16(Ab + aSrc[i] + nxt, dst + (i * GT + t) * 16);
        stage16(Bb + bSrc[i] + nxt, dst + BM * BKQ + (i * GT + t) * 16);
      }
    }
    const char* ldsA = lds + cur * BUF;
    const char* ldsB = ldsA + BM * BKQ;

#pragma unroll
    for (int ks = 0; ks < 2; ++ks) {        // two K=64 MFMA steps per BKQ=128
      const int xo = xc0 ^ (ks * 64);
      i32x4 af[4], bfr[2];
#pragma unroll
      for (int mi = 0; mi < 4; ++mi)
        af[mi] = *(const i32x4*)(ldsA + aRowB + mi * 2048 + xo);
#pragma unroll
      for (int ni = 0; ni < 2; ++ni)
        bfr[ni] = *(const i32x4*)(ldsB + bRowB + ni * 2048 + xo);
#pragma unroll
      for (int mi = 0; mi < 4; ++mi)
#pragma unroll
        for (int ni = 0; ni < 2; ++ni)
          acc[mi][ni] = __builtin_amdgcn_mfma_i32_16x16x64_i8(
              af[mi], bfr[ni], acc[mi][ni], 0, 0, 0);
    }
    __syncthreads();   // one barrier per K-step: drains t+1 loads, guards reuse
    cur ^= 1;
  }

  const float mx = fmaxf(__uint_as_float(*slot), 1e-20f);
  const float sc = mx * (1.0f / 16129.0f);  // / (127*127)

  const int mBase = m0 + wm * 64 + quad * 4;
  const int nBase = n0 + wn * 32 + l15;
  bf16_t* Cb = C + (size_t)z * sC;
#pragma unroll
  for (int mi = 0; mi < 4; ++mi) {
#pragma unroll
    for (int j = 0; j < 4; ++j) {
      size_t rowOff = (size_t)(mBase + mi * 16 + j) * (size_t)N;
#pragma unroll
      for (int ni = 0; ni < 2; ++ni)
        Cb[rowOff + nBase + ni * 16] = __float2bfloat16((float)acc[mi][ni][j] * sc);
    }
  }
}

// Sum SK bf16 partial chunks (stride tot) in fp32; write bf16 or f32.
// AMAX: fuse per-tensor absmax of the summed outputs (block max -> 1 atomic).
// CONTRACT: (tot/8) % (gridDim.x * blockDim.x * 2) == 0 at every call site.
template <int SK, bool F32OUT, bool AMAX>
__global__ void reduce_k(const bf16_t* __restrict__ pp, void* __restrict__ out,
                         size_t tot, unsigned* __restrict__ amax) {
  const int bs = blockDim.x;
  size_t base = (size_t)blockIdx.x * bs * 2 + threadIdx.x;  // 8-elem group idx
  bf16x8 v[2][SK];
#pragma unroll
  for (int u = 0; u < 2; ++u) {
    size_t g = base + (size_t)u * bs;
#pragma unroll
    for (int kz = 0; kz < SK; ++kz)
      v[u][kz] = *(const bf16x8*)(pp + (size_t)kz * tot + g * 8);
  }
  float mval = 0.f;
#pragma unroll
  for (int u = 0; u < 2; ++u) {
    size_t g = base + (size_t)u * bs;
    float s[8];
#pragma unroll
    for (int j = 0; j < 8; ++j) s[j] = 0.f;
#pragma unroll
    for (int kz = 0; kz < SK; ++kz)
#pragma unroll
      for (int j = 0; j < 8; ++j) s[j] += (float)v[u][kz][j];
    if (AMAX) {
#pragma unroll
      for (int j = 0; j < 8; ++j) mval = fmaxf(mval, fabsf(s[j]));
    }
    if (F32OUT) {
      float* o = (float*)out + g * 8;
      float4 r0{s[0], s[1], s[2], s[3]};
      float4 r1{s[4], s[5], s[6], s[7]};
      ((float4*)o)[0] = r0;
      ((float4*)o)[1] = r1;
    } else {
      uint4 r;
      r.x = pk2(s[0], s[1]);
      r.y = pk2(s[2], s[3]);
      r.z = pk2(s[4], s[5]);
      r.w = pk2(s[6], s[7]);
      *(uint4*)((bf16_t*)out + g * 8) = r;
    }
  }
  if (AMAX) block_max_commit(mval, amax);
}

// ---------------- fused prep kernel (one launch, partitioned grid) ----------
// Segment A (blocks [0,512)):          absmax(x) -> SX  (grid-stride, 2 iters)
// Segment B (blocks [512,512+3584)):   W1/W2/W3 transpose+cast. 3584*256 =
//                                      917504 = n1+n2+n3 EXACTLY (R2 bug: 5120
//                                      here overran W3T by ~1MB, clobbering SC).
// Segment C (blocks [4096,4096+16384)): AW_q = round(adj*S*127), 1 float4/thr.
//   R7 CONFIRMED: nontemporal loads on adj/S dropped prep out of the top-5
//   (was 59us) -- the 134MB read-once stream was polluting the cache
//   hierarchy. KEEP nt. AWQ store stays cached (re-read 3x by gemms).
// SX/SH1/SST3 slots are zeroed by a hipMemsetAsync node BEFORE this kernel.
#define PREP_AMX 512
#define PREP_C3  3584   // (256*512 + 512*1024 + 1024*256) / 256  == 3584
#define PREP_MC  16384  // (4096*4096/4) / 256

__global__ void prep_kernel(const float* __restrict__ adj, const float* __restrict__ S,
                            int8_t* __restrict__ o,
                            const float* __restrict__ x, size_t n4x,
                            unsigned* __restrict__ SX,
                            const float* __restrict__ W1, const float* __restrict__ W2,
                            const float* __restrict__ W3, bf16_t* __restrict__ W1T,
                            bf16_t* __restrict__ W2T, bf16_t* __restrict__ W3T) {
  const int bid = blockIdx.x;
  const int tid = threadIdx.x;

  if (bid < PREP_AMX) {
    // absmax over x (f32), 4 float4 loads in flight per iter
    size_t base = (size_t)bid * (256 * 4) + tid;
    const size_t stride = (size_t)PREP_AMX * 256 * 4;
    float m = 0.f;
    for (; base + 3 * 256 < n4x; base += stride) {
      float4 v[4];
#pragma unroll
      for (int j = 0; j < 4; ++j) v[j] = ((const float4*)x)[base + (size_t)j * 256];
#pragma unroll
      for (int j = 0; j < 4; ++j)
        m = fmaxf(m, fmaxf(fmaxf(fabsf(v[j].x), fabsf(v[j].y)),
                           fmaxf(fabsf(v[j].z), fabsf(v[j].w))));
    }
    block_max_commit(m, SX);
  } else if (bid < PREP_AMX + PREP_C3) {
    const int n1 = 256 * 512;
    const int n2 = 512 * 1024;
    const int n3 = 1024 * 256;
    int idx = (bid - PREP_AMX) * 256 + tid;
    if (idx < n1) {
      int K = 256, H = 512;
      int h = idx / K, k = idx - h * K;
      W1T[idx] = __float2bfloat16(W1[(size_t)k * H + h]);
    } else if (idx < n1 + n2) {
      int i = idx - n1;
      int K = 512, H = 1024;
      int h = i / K, k = i - h * K;
      W2T[i] = __float2bfloat16(W2[(size_t)k * H + h]);
    } else if (idx < n1 + n2 + n3) {
      int i = idx - n1 - n2;
      int K = 1024, H = 256;
      int h = i / K, k = i - h * K;
      W3T[i] = __float2bfloat16(W3[(size_t)k * H + h]);
    }
  } else {
    int i = (bid - PREP_AMX - PREP_C3) * 256 + tid;
    f32x4 av = __builtin_nontemporal_load((const f32x4*)adj + i);
    f32x4 sv = __builtin_nontemporal_load((const f32x4*)S + i);
    float v0 = av[0] * sv[0] * 127.f, v1 = av[1] * sv[1] * 127.f;
    float v2 = av[2] * sv[2] * 127.f, v3 = av[3] * sv[3] * 127.f;
    int q0 = (int)rintf(fminf(fmaxf(v0, -127.f), 127.f));
    int q1 = (int)rintf(fminf(fmaxf(v1, -127.f), 127.f));
    int q2 = (int)rintf(fminf(fmaxf(v2, -127.f), 127.f));
    int q3 = (int)rintf(fminf(fmaxf(v3, -127.f), 127.f));
    unsigned p = (unsigned)(q0 & 255) | ((unsigned)(q1 & 255) << 8) |
                 ((unsigned)(q2 & 255) << 16) | ((unsigned)(q3 & 255) << 24);
    ((unsigned*)o)[i] = p;
  }
}

// x [B][4096][256] f32 -> xt [B][256][4096] i8 (scale 127/mx from slot)
__global__ void transpose_quant_x(const float* __restrict__ x, int8_t* __restrict__ xt,
                                  const unsigned* __restrict__ slot) {
  __shared__ float tile[32][33];
  const int N = 4096, F = 256;
  float qs = 127.0f / fmaxf(__uint_as_float(*slot), 1e-20f);
  int n0 = blockIdx.x * 32, f0 = blockIdx.y * 32, b = blockIdx.z;
  const float* xb = x + (size_t)b * N * F;
  int8_t* xtb = xt + (size_t)b * N * F;
  int tx = threadIdx.x & 31, ty = threadIdx.x >> 5;  // 32 x 8
#pragma unroll
  for (int i = 0; i < 32; i += 8)
    tile[ty + i][tx] = xb[(size_t)(n0 + ty + i) * F + f0 + tx];
  __syncthreads();
#pragma unroll
  for (int i = 0; i < 32; i += 8) {
    float v = tile[tx][ty + i] * qs;
    xtb[(size_t)(f0 + ty + i) * N + n0 + tx] =
        (int8_t)(int)rintf(fminf(fmaxf(v, -127.f), 127.f));
  }
}

// bf16 -> i8 with scale 127/mx from slot; 4 groups of 8 elems per thread.
// CONTRACT: n8 % (gridDim.x * blockDim.x * 4) == 0 at every call site.
__global__ void quant8(const bf16_t* __restrict__ in, int8_t* __restrict__ out,
                       const unsigned* __restrict__ slot, size_t n8) {
  const int bs = blockDim.x;
  size_t base = (size_t)blockIdx.x * bs * 4 + threadIdx.x;
  float qs = 127.0f / fmaxf(__uint_as_float(*slot), 1e-20f);
  bf16x8 v[4];
#pragma unroll
  for (int j = 0; j < 4; ++j)
    v[j] = *(const bf16x8*)(in + (base + (size_t)j * bs) * 8);
#pragma unroll
  for (int j = 0; j < 4; ++j) {
    unsigned lo = 0, hi = 0;
#pragma unroll
    for (int e = 0; e < 4; ++e) {
      int q = (int)rintf(fminf(fmaxf((float)v[j][e] * qs, -127.f), 127.f));
      lo |= (unsigned)(q & 255) << (8 * e);
    }
#pragma unroll
    for (int e = 0; e < 4; ++e) {
      int q = (int)rintf(fminf(fmaxf((float)v[j][4 + e] * qs, -127.f), 127.f));
      hi |= (unsigned)(q & 255) << (8 * e);
    }
    uint2 r{lo, hi};
    ((uint2*)out)[base + (size_t)j * bs] = r;
  }
}

extern "C" void kernel_launch(void* const* d_in, const int* in_sizes, int n_in,
                              void* d_out, int out_size, void* d_ws, size_t ws_size,
                              hipStream_t stream) {
  const float* x   = (const float*)d_in[0];  // [4, 4096, 256]
  const float* adj = (const float*)d_in[1];  // [4096, 4096]
  const float* S   = (const float*)d_in[2];  // [4096, 4096]
  const float* W1  = (const float*)d_in[3];  // [256, 512]
  const float* W2  = (const float*)d_in[4];  // [512, 1024]
  const float* W3  = (const float*)d_in[5];  // [1024, 256]

  const int N = 4096, F = 256, H1 = 512, H2 = 1024, NC = 256, B = 4;

  // Chain (adjacency GEMMs i8, support GEMMs bf16), R7 workspace (~98.5 MiB):
  char* ws = (char*)d_ws;
  int8_t* AWQ  = (int8_t*)ws; ws += (size_t)N * N;           // 16.8 MB
  bf16_t* SCR  = (bf16_t*)ws; ws += (size_t)B * N * H2 * 2;  // 33.5 MB partials/H2B
  int8_t* XQT  = (int8_t*)ws; ws += (size_t)B * F * N;       //  4.2 MB
  bf16_t* BufY = (bf16_t*)ws; ws += (size_t)B * N * H1 * 2;  // 16.8 MB G2/ST3T
  bf16_t* BufZ = (bf16_t*)ws; ws += (size_t)B * N * H1 * 2;  // 16.8 MB H1T/st3 partials
  int8_t* QS   = (int8_t*)ws; ws += (size_t)B * H1 * N;      //  8.4 MB H1Q/ST3Q
  bf16_t* W1T  = (bf16_t*)ws; ws += (size_t)F * H1 * 2;
  bf16_t* W2T  = (bf16_t*)ws; ws += (size_t)H1 * H2 * 2;
  bf16_t* W3T  = (bf16_t*)ws; ws += (size_t)H2 * NC * 2;
  unsigned* SC = (unsigned*)ws;                              // 3 scale slots
  unsigned* SX = SC, *SH1 = SC + 1, *SST3 = SC + 2;

  bf16_t* G2 = BufY, *ST3T = BufY;
  bf16_t* H1T = BufZ;
  bf16_t* H2B = SCR;
  int8_t* H1Q = QS, *ST3Q = QS;

  dim3 blkG(GT);   // 512-thread gemm blocks (R11)

  // prep: zero the 3 scale slots (graph-legal memset node), then one fused
  // kernel: absmax(x) | weight cast3 | AW_q quantize (nt loads).
  (void)hipMemsetAsync(SC, 0, 3 * sizeof(unsigned), stream);
  prep_kernel<<<PREP_AMX + PREP_C3 + PREP_MC, 256, 0, stream>>>(
      adj, S, AWQ, x, (size_t)B * N * F / 4, SX, W1, W2, W3, W1T, W2T, W3T);
  transpose_quant_x<<<dim3(N / 32, F / 32, B), 256, 0, stream>>>(x, XQT, SX);

  // L1: g1 = AWq @ xq, SK=2 -> SCR partials P0 (z=0..3) and P1 (z=4..7).
  //     Grid (32,2,8) = 512 blocks.
  gemm_i8<<<dim3(N / BM, F / BN, B * 2), blkG, 0, stream>>>(
      AWQ, XQT, SCR, N, F, N, N / 2, 0, (long)F * N, (long)N * F, SX);
  //     h1^T = relu((P0+P1) @ W1)^T via DUAL-A (R10; GEMM linear in A).
  //     absmax fused into epilogue -> SH1.
  gemm_bt<1, true, true><<<dim3(N / BM, H1 / BN, B), blkG, 0, stream>>>(
      SCR, W1T, H1T, N, H1, F, F, (long)N * F, 0, (long)H1 * N, SH1,
      SCR + (size_t)4 * N * F);
  // n8 = 1,048,576 ; 1024*256*4 = 1,048,576 -> exact single shot.
  quant8<<<1024, 256, 0, stream>>>(H1T, H1Q, SH1, (size_t)B * H1 * N / 8);

  // L2: g2 = AWq @ h1q, NO split-K (direct write -> G2). Grid (32,4,4) = 512.
  gemm_i8<<<dim3(N / BM, H1 / BN, B), blkG, 0, stream>>>(
      AWQ, H1Q, G2, N, H1, N, N, 0, (long)H1 * N, (long)N * H1, SH1);
  //     h2 = relu(g2 @ W2) -> H2B (SCR).  Grid (32,8,4) = 1024.
  gemm_bt<0, true, false><<<dim3(N / BM, H2 / BN, B), blkG, 0, stream>>>(
      G2, W2T, H2B, N, H2, H1, H1, (long)N * H1, 0, (long)N * H2, nullptr,
      nullptr);

  // L3: st3^T = (h2 @ W3)^T, SK=2 -> partials BufZ, reduce+absmax -> ST3T/SST3
  gemm_bt<1, false, false><<<dim3(N / BM, NC / BN, B * 2), blkG, 0, stream>>>(
      H2B, W3T, BufZ, N, NC, H2, H2 / 2, (long)N * H2, 0, (long)NC * N, nullptr,
      nullptr);
  // groups = 524,288 -> 1024 blocks exact.
  reduce_k<2, false, true><<<1024, 256, 0, stream>>>(BufZ, ST3T, (size_t)B * NC * N, SST3);
  // n8 = 524,288 ; 512*256*4 = 524,288 -> exact single shot.
  quant8<<<512, 256, 0, stream>>>(ST3T, ST3Q, SST3, (size_t)B * NC * N / 8);
  //     out = AWq @ st3q, SK=2 -> partials SCR, reduce f32 -> d_out
  gemm_i8<<<dim3(N / BM, NC / BN, B * 2), blkG, 0, stream>>>(
      AWQ, ST3Q, SCR, N, NC, N, N / 2, 0, (long)NC * N, (long)N * NC, SST3);
  // groups = 524,288 -> 1024 blocks exact.
  reduce_k<2, true, false><<<1024, 256, 0, stream>>>(SCR, d_out, (size_t)B * N * NC, nullptr);
}